// Round 5
// baseline (637.267 us; speedup 1.0000x reference)
//
#include <hip/hip_runtime.h>
#include <math.h>

#define NHW   9216     // 96*96
#define NROWS 36864    // NHW*4

typedef _Float16 f16;
typedef _Float16 f16x8 __attribute__((ext_vector_type(8)));
typedef float    f32x4 __attribute__((ext_vector_type(4)));

__device__ __forceinline__ float softplusf(float x) {
    return fmaxf(x, 0.f) + log1pf(expf(-fabsf(x)));
}

// ---------------- positional encoding ctx[hw][128] ----------------
__global__ __launch_bounds__(256) void ctx_kernel(float* __restrict__ ctx) {
    int e = blockIdx.x * 256 + threadIdx.x;
    if (e >= NHW * 128) return;
    int c  = e & 127;
    int hw = e >> 7;
    int i = hw / 96, j = hw % 96;
    int pos = (c < 64) ? i : j;
    int cc = c & 63;
    int k = cc >> 1;
    float invf = powf(10000.f, -(float)k / 32.f);
    float v = (float)pos * invf;
    ctx[e] = (cc & 1) ? cosf(v) : sinf(v);
}

// ---------------- spatial_norm -> z[row][16], row = (i*96+j)*4+b ----------------
__global__ __launch_bounds__(256) void snorm_kernel(const float* __restrict__ x,
                                                    float* __restrict__ z) {
    int e = blockIdx.x * 256 + threadIdx.x;
    if (e >= NROWS * 16) return;
    int j = e % 96;
    int i = (e / 96) % 96;
    int s = (e / 9216) % 16;
    int b = e / (9216 * 16);
    float sum = 0.f;
    const float* xb = x + (size_t)((b * 16 + s) * 3) * 192 * 192;
    #pragma unroll
    for (int c = 0; c < 3; ++c) {
        const float* xc = xb + (size_t)c * 192 * 192;
        #pragma unroll
        for (int dh = -1; dh <= 1; ++dh) {
            int hh = 2 * i + dh;
            if (hh < 0 || hh >= 192) continue;
            const float* xr = xc + hh * 192;
            #pragma unroll
            for (int dw = -1; dw <= 1; ++dw) {
                int ww = 2 * j + dw;
                if (ww < 0 || ww >= 192) continue;
                float v = xr[ww];
                sum += v * v;
            }
        }
    }
    int row = (i * 96 + j) * 4 + b;
    z[(size_t)row * 16 + s] = sqrtf(sum);
}

// ---------------- init logq with sum of LU log-dets (constant) ----------------
__global__ __launch_bounds__(256) void initlogq_kernel(const float* __restrict__ lu_udiag,
                                                       float* __restrict__ logq) {
    int row = blockIdx.x * 256 + threadIdx.x;
    if (row >= NROWS) return;
    float c0 = 0.f;
    for (int k = 0; k < 64; ++k)
        c0 += logf(softplusf(lu_udiag[k]) + 0.001f);
    logq[row] = c0;
}

// ---------------- LU transform: z = L(U z_perm) + bias (in place per row) ----------------
__global__ __launch_bounds__(256) void lu_kernel(float* __restrict__ z,
                                                 const float* __restrict__ lower,
                                                 const float* __restrict__ upper,
                                                 const float* __restrict__ udiag_raw,
                                                 const float* __restrict__ bias,
                                                 const int* __restrict__ perm) {
    int row = blockIdx.x * 256 + threadIdx.x;
    if (row >= NROWS) return;
    float* zr = z + (size_t)row * 16;
    float zp[16], y[16];
    #pragma unroll
    for (int d = 0; d < 16; ++d) zp[d] = zr[perm[d]];
    #pragma unroll
    for (int r = 0; r < 16; ++r) {
        float acc = (softplusf(udiag_raw[r]) + 0.001f) * zp[r];
        #pragma unroll
        for (int c = 0; c < 16; ++c)
            if (c > r) acc += upper[r * 16 + c] * zp[c];
        y[r] = acc;
    }
    #pragma unroll
    for (int r = 0; r < 16; ++r) {
        float acc = y[r] + bias[r];
        #pragma unroll
        for (int c = 0; c < 16; ++c)
            if (c < r) acc += lower[r * 16 + c] * y[c];
        zr[r] = acc;
    }
}

// ---------------- one-time weight pack kernel ----------------
// MFMA B-fragment order for a [N][K] weight (K=128): frag element
//   f = ((nt*4+ks)*64 + l)*8 + j  ->  n = nt*16+(l&15), k = ks*32+((l>>4)&3)*8+j
// cat 0: fW1f (f16) 8 mats x16384 = T-frag(sp_bW1)
// cat 1: fW2f (f16)
// cat 2: mW1f (f16) 2 mats, MASK_HID
// cat 3: mW2f (f16) 2 mats, MASK_HID
// cat 4: fWoutf (f16) 4 x 12nt x4ks x64 x8 (184 cols padded to 192)
// cat 5: mWoutf (f16) 2nt, MASK_OUT
// cat 6: finf[4][4096] f16: input-layer frags, K=32 pad (k<8 = even-z weights)
// cat 7: minf[4096]  f16: MADE input frags, K=32 pad (k<16, MASK_IN)
// cat 8: fpw[4][384][128]; cat 9: mpw[384][128]; cat 10: fpb; cat 11: mpb
__global__ __launch_bounds__(256) void pack_kernel(
    const float* __restrict__ sp_bW1, const float* __restrict__ sp_bW2,
    const float* __restrict__ made_bW1, const float* __restrict__ made_bW2,
    const float* __restrict__ sp_Wout, const float* __restrict__ made_Wout,
    const float* __restrict__ sp_Win, const float* __restrict__ made_W0,
    const float* __restrict__ sp_bCW, const float* __restrict__ made_ctxW,
    const float* __restrict__ made_bCW,
    const float* __restrict__ sp_bin, const float* __restrict__ sp_bCb,
    const float* __restrict__ made_ctxb, const float* __restrict__ made_b0,
    const float* __restrict__ made_bCb,
    f16* __restrict__ fW1f, f16* __restrict__ fW2f,
    f16* __restrict__ mW1f, f16* __restrict__ mW2f,
    f16* __restrict__ fWoutf, f16* __restrict__ mWoutf,
    f16* __restrict__ finf, f16* __restrict__ minf,
    float* __restrict__ fpw, float* __restrict__ mpw,
    float* __restrict__ fpb, float* __restrict__ mpb)
{
    int cat = blockIdx.y;
    int e = blockIdx.x * 256 + threadIdx.x;
    switch (cat) {
    case 0: if (e < 8 * 16384) {
        int mtx = e >> 14, f = e & 16383;
        int nt = f >> 11, ks = (f >> 9) & 3, l = (f >> 3) & 63, j = f & 7;
        int n = nt * 16 + (l & 15), k = ks * 32 + ((l >> 4) & 3) * 8 + j;
        fW1f[e] = (f16)sp_bW1[mtx * 16384 + n * 128 + k];
    } break;
    case 1: if (e < 8 * 16384) {
        int mtx = e >> 14, f = e & 16383;
        int nt = f >> 11, ks = (f >> 9) & 3, l = (f >> 3) & 63, j = f & 7;
        int n = nt * 16 + (l & 15), k = ks * 32 + ((l >> 4) & 3) * 8 + j;
        fW2f[e] = (f16)sp_bW2[mtx * 16384 + n * 128 + k];
    } break;
    case 2: if (e < 2 * 16384) {
        int mtx = e >> 14, f = e & 16383;
        int nt = f >> 11, ks = (f >> 9) & 3, l = (f >> 3) & 63, j = f & 7;
        int n = nt * 16 + (l & 15), k = ks * 32 + ((l >> 4) & 3) * 8 + j;
        mW1f[e] = ((n % 15) >= (k % 15)) ? (f16)made_bW1[mtx * 16384 + n * 128 + k] : (f16)0.f;
    } break;
    case 3: if (e < 2 * 16384) {
        int mtx = e >> 14, f = e & 16383;
        int nt = f >> 11, ks = (f >> 9) & 3, l = (f >> 3) & 63, j = f & 7;
        int n = nt * 16 + (l & 15), k = ks * 32 + ((l >> 4) & 3) * 8 + j;
        mW2f[e] = ((n % 15) >= (k % 15)) ? (f16)made_bW2[mtx * 16384 + n * 128 + k] : (f16)0.f;
    } break;
    case 4: if (e < 4 * 24576) {
        int s = e / 24576, f = e % 24576;
        int nt = f >> 11, ks = (f >> 9) & 3, l = (f >> 3) & 63, j = f & 7;
        int n = nt * 16 + (l & 15), k = ks * 32 + ((l >> 4) & 3) * 8 + j;
        fWoutf[e] = (n < 184) ? (f16)sp_Wout[s * 23552 + n * 128 + k] : (f16)0.f;
    } break;
    case 5: if (e < 4096) {
        int f = e;
        int nt = f >> 11, ks = (f >> 9) & 3, l = (f >> 3) & 63, j = f & 7;
        int n = nt * 16 + (l & 15), k = ks * 32 + ((l >> 4) & 3) * 8 + j;
        mWoutf[e] = (((n & 15) > (k % 15)) && n < 32) ? (f16)made_Wout[n * 128 + k] : (f16)0.f;
    } break;
    case 6: if (e < 4 * 4096) {
        int s = e >> 12, f = e & 4095;
        int nt = f >> 9, l = (f >> 3) & 63, j = f & 7;
        int n = nt * 16 + (l & 15), k = ((l >> 4) & 3) * 8 + j;
        finf[e] = (k < 8) ? (f16)sp_Win[s * 17408 + n * 136 + k] : (f16)0.f;
    } break;
    case 7: if (e < 4096) {
        int f = e;
        int nt = f >> 9, l = (f >> 3) & 63, j = f & 7;
        int n = nt * 16 + (l & 15), k = ((l >> 4) & 3) * 8 + j;
        minf[e] = (k < 16 && (n % 15) >= k) ? (f16)made_W0[n * 16 + k] : (f16)0.f;
    } break;
    case 8: if (e < 4 * 49152) {
        int s = e / 49152, r = e % 49152, n = r >> 7, k = r & 127;
        float v;
        if (n < 128)      v = sp_Win[s * 17408 + n * 136 + 8 + k];
        else if (n < 256) v = sp_bCW[(size_t)(s * 2 + 0) * 16384 + (n - 128) * 128 + k];
        else              v = sp_bCW[(size_t)(s * 2 + 1) * 16384 + (n - 256) * 128 + k];
        fpw[e] = v;
    } break;
    case 9: if (e < 49152) {
        int n = e >> 7, k = e & 127;
        float v;
        if (n < 128)      v = made_ctxW[n * 128 + k];
        else if (n < 256) v = made_bCW[(n - 128) * 128 + k];
        else              v = made_bCW[16384 + (n - 256) * 128 + k];
        mpw[e] = v;
    } break;
    case 10: if (e < 4 * 384) {
        int s = e / 384, n = e % 384;
        float v;
        if (n < 128)      v = sp_bin[s * 128 + n];
        else if (n < 256) v = sp_bCb[(s * 2 + 0) * 128 + (n - 128)];
        else              v = sp_bCb[(s * 2 + 1) * 128 + (n - 256)];
        fpb[e] = v;
    } break;
    case 11: if (e < 384) {
        float v;
        if (e < 128)      v = made_ctxb[e] + made_b0[e];
        else if (e < 256) v = made_bCb[e - 128];
        else              v = made_bCb[128 + (e - 256)];
        mpb[e] = v;
    } break;
    }
}

// ---------------- tiled f32 GEMM (ctx / encoder): C = post(A @ W^T + bias) ----------------
// POST: 0 store, 2 silu, 4 mixed (n<128 store, else sigmoid)
template<int POST>
__global__ __launch_bounds__(256) void gemm_k(
    const float* __restrict__ A, int lda,
    const float* __restrict__ W, int ldw,
    const float* __restrict__ bias,
    float* __restrict__ C, int ldc,
    int M, int N, int K)
{
    __shared__ alignas(16) float As[16][68];
    __shared__ alignas(16) float Ws[16][68];
    const int tid = threadIdx.x;
    const int m0 = blockIdx.x * 64;
    const int n0 = blockIdx.y * 64;
    const int tm = (tid >> 4) << 2;
    const int tn = (tid & 15) << 2;
    const int srow = tid >> 2;
    const int skq  = (tid & 3) << 2;

    float acc[4][4] = {{0.f,0.f,0.f,0.f},{0.f,0.f,0.f,0.f},{0.f,0.f,0.f,0.f},{0.f,0.f,0.f,0.f}};

    for (int k0 = 0; k0 < K; k0 += 16) {
        float4 av = *(const float4*)(A + (size_t)(m0 + srow) * lda + k0 + skq);
        As[skq + 0][srow] = av.x; As[skq + 1][srow] = av.y;
        As[skq + 2][srow] = av.z; As[skq + 3][srow] = av.w;
        int wn = n0 + srow;
        float4 wv = make_float4(0.f, 0.f, 0.f, 0.f);
        if (wn < N) wv = *(const float4*)(W + (size_t)wn * ldw + k0 + skq);
        Ws[skq + 0][srow] = wv.x; Ws[skq + 1][srow] = wv.y;
        Ws[skq + 2][srow] = wv.z; Ws[skq + 3][srow] = wv.w;
        __syncthreads();
        #pragma unroll
        for (int kk = 0; kk < 16; ++kk) {
            float4 a4 = *(const float4*)&As[kk][tm];
            float4 w4 = *(const float4*)&Ws[kk][tn];
            float aa[4] = {a4.x, a4.y, a4.z, a4.w};
            float wwv[4] = {w4.x, w4.y, w4.z, w4.w};
            #pragma unroll
            for (int q = 0; q < 4; ++q)
                #pragma unroll
                for (int r = 0; r < 4; ++r)
                    acc[q][r] = fmaf(aa[q], wwv[r], acc[q][r]);
        }
        __syncthreads();
    }
    #pragma unroll
    for (int q = 0; q < 4; ++q) {
        int m = m0 + tm + q;
        #pragma unroll
        for (int r = 0; r < 4; ++r) {
            int n = n0 + tn + r;
            if (n < N) {
                float val = acc[q][r] + bias[n];
                float* cp = C + (size_t)m * ldc + n;
                if (POST == 0)      *cp = val;
                else if (POST == 2) *cp = val / (1.f + expf(-val));
                else                *cp = (n < 128) ? val : 1.f / (1.f + expf(-val));
            }
        }
    }
}

// ---------------- MFMA mega kernel: input layer + 2 residual blocks + Wout ----------------
// block = 256 threads = 4 waves; each wave owns a PRIVATE 16-row stripe -> NO barriers.
// Input layer is MFMA too (K padded to 32); acc C-init carries the thw/ctx term
// (4 consecutive rows share one hw, so all 4 D-regs take the same value).
// Fragment maps (verified in round 4): A: a[j]=src[l&15][ks*32+(l>>4)*8+j];
// B: b[j]=W[n=nt*16+(l&15)][same k]; D: row=(l>>4)*4+r, col=nt*16+(l&15).
template<int MODE>   // 0 flow (NOUT=184, even-z input), 1 made (NOUT=32, all-z input)
__global__ __launch_bounds__(256) void mega_mfma(
    const float* __restrict__ zg,       // [36864][16]
    const float* __restrict__ ctxout,   // [9216][384] thw | gate1 | gate2 (pre-sigmoided)
    const f16*  __restrict__ inf,       // [8*64*8] input-layer B-frags (K=32 pad)
    const f16*  __restrict__ W1f,       // [2][16384]
    const f16*  __restrict__ W2f,       // [2][16384]
    const float* __restrict__ bb1,      // [2][128]
    const float* __restrict__ bb2,      // [2][128]
    const f16*  __restrict__ Woutf,     // [NTO*2048]
    const float* __restrict__ boutv,    // [NOUT]
    float* __restrict__ p)              // [36864][NOUT]
{
    constexpr int NOUT = MODE ? 32 : 184;
    constexpr int NTO  = MODE ? 2 : 12;
    __shared__ alignas(16) f16 tS[4][16][136];
    __shared__ alignas(16) f16 uS[4][16][136];
    __shared__ alignas(16) f16 zS[4][16][32];
    const int tid = threadIdx.x;
    const int w   = tid >> 6;          // wave 0..3
    const int l   = tid & 63;
    const int m0  = blockIdx.x * 64 + w * 16;
    const int lr  = l & 15;
    const int lq  = l >> 4;
    const int hwq = (m0 >> 2) + lq;    // hw for this lane-quarter's 4 rows

    // ---- stage z tile: one coalesced float4 per lane ----
    {
        const int r = l >> 2, cq = l & 3;
        const f16x8 zzero = {(f16)0.f,(f16)0.f,(f16)0.f,(f16)0.f,
                             (f16)0.f,(f16)0.f,(f16)0.f,(f16)0.f};
        if (MODE == 0) { if (cq < 3) *(f16x8*)&zS[w][r][8 + cq * 8] = zzero; }
        else           { if (cq < 2) *(f16x8*)&zS[w][r][16 + cq * 8] = zzero; }
        float4 zv = *(const float4*)(zg + (size_t)(m0 + r) * 16 + cq * 4);
        if (MODE == 0) {           // even dims only
            zS[w][r][cq * 2 + 0] = (f16)zv.x;
            zS[w][r][cq * 2 + 1] = (f16)zv.z;
        } else {
            zS[w][r][cq * 4 + 0] = (f16)zv.x;
            zS[w][r][cq * 4 + 1] = (f16)zv.y;
            zS[w][r][cq * 4 + 2] = (f16)zv.z;
            zS[w][r][cq * 4 + 3] = (f16)zv.w;
        }
    }

    // ---- input layer MFMA: t = thw + z_in @ Win_z ----
    {
        f16x8 a = *(const f16x8*)&zS[w][lr][lq * 8];
        const float* cb = ctxout + (size_t)hwq * 384;
        #pragma unroll
        for (int nt = 0; nt < 8; ++nt) {
            float thw = cb[nt * 16 + lr];
            f32x4 c = {thw, thw, thw, thw};
            f16x8 b = *(const f16x8*)(inf + (nt * 64 + l) * 8);
            c = __builtin_amdgcn_mfma_f32_16x16x32_f16(a, b, c, 0, 0, 0);
            #pragma unroll
            for (int r = 0; r < 4; ++r)
                tS[w][lq * 4 + r][nt * 16 + lr] = (f16)c[r];
        }
    }

    const f32x4 vzero = {0.f, 0.f, 0.f, 0.f};

    // ---- residual blocks (wave-private; no barriers) ----
    #pragma unroll
    for (int blk = 0; blk < 2; ++blk) {
        f32x4 acc[8];
        #pragma unroll
        for (int nt = 0; nt < 8; ++nt) acc[nt] = vzero;
        #pragma unroll
        for (int ks = 0; ks < 4; ++ks) {
            f16x8 a = *(const f16x8*)&tS[w][lr][ks * 32 + lq * 8];
            #pragma unroll
            for (int j = 0; j < 8; ++j) a[j] = a[j] > (f16)0.f ? a[j] : (f16)0.f;
            const f16* wb = W1f + (size_t)blk * 16384 + (ks * 64 + l) * 8;
            #pragma unroll
            for (int nt = 0; nt < 8; ++nt) {
                f16x8 b = *(const f16x8*)(wb + nt * 2048);
                acc[nt] = __builtin_amdgcn_mfma_f32_16x16x32_f16(a, b, acc[nt], 0, 0, 0);
            }
        }
        #pragma unroll
        for (int nt = 0; nt < 8; ++nt) {
            float bias = bb1[blk * 128 + nt * 16 + lr];
            #pragma unroll
            for (int r = 0; r < 4; ++r)
                uS[w][lq * 4 + r][nt * 16 + lr] = (f16)(acc[nt][r] + bias);
        }

        #pragma unroll
        for (int nt = 0; nt < 8; ++nt) acc[nt] = vzero;
        #pragma unroll
        for (int ks = 0; ks < 4; ++ks) {
            f16x8 a = *(const f16x8*)&uS[w][lr][ks * 32 + lq * 8];
            #pragma unroll
            for (int j = 0; j < 8; ++j) a[j] = a[j] > (f16)0.f ? a[j] : (f16)0.f;
            const f16* wb = W2f + (size_t)blk * 16384 + (ks * 64 + l) * 8;
            #pragma unroll
            for (int nt = 0; nt < 8; ++nt) {
                f16x8 b = *(const f16x8*)(wb + nt * 2048);
                acc[nt] = __builtin_amdgcn_mfma_f32_16x16x32_f16(a, b, acc[nt], 0, 0, 0);
            }
        }
        {
            const float* gb = ctxout + (size_t)hwq * 384 + 128 + blk * 128;
            #pragma unroll
            for (int nt = 0; nt < 8; ++nt) {
                float bias = bb2[blk * 128 + nt * 16 + lr];
                float g = gb[nt * 16 + lr];
                #pragma unroll
                for (int r = 0; r < 4; ++r) {
                    float tv = (float)tS[w][lq * 4 + r][nt * 16 + lr];
                    tS[w][lq * 4 + r][nt * 16 + lr] = (f16)(tv + (acc[nt][r] + bias) * g);
                }
            }
        }
    }

    // ---- output projection: p = t @ Wout + bout (no relu) ----
    f32x4 po[NTO];
    #pragma unroll
    for (int nt = 0; nt < NTO; ++nt) po[nt] = vzero;
    #pragma unroll
    for (int ks = 0; ks < 4; ++ks) {
        f16x8 a = *(const f16x8*)&tS[w][lr][ks * 32 + lq * 8];
        const f16* wb = Woutf + (ks * 64 + l) * 8;
        #pragma unroll
        for (int nt = 0; nt < NTO; ++nt) {
            f16x8 b = *(const f16x8*)(wb + nt * 2048);
            po[nt] = __builtin_amdgcn_mfma_f32_16x16x32_f16(a, b, po[nt], 0, 0, 0);
        }
    }
    #pragma unroll
    for (int nt = 0; nt < NTO; ++nt) {
        int n = nt * 16 + lr;
        if (n < NOUT) {
            float bias = boutv[n];
            #pragma unroll
            for (int r = 0; r < 4; ++r) {
                int gm = m0 + lq * 4 + r;
                p[(size_t)gm * NOUT + n] = po[nt][r] + bias;
            }
        }
    }
}

// ---------------- rational-quadratic spline ----------------
__device__ __forceinline__ void knots8(const float* __restrict__ u, float* c, float* w) {
    float mx = u[0];
    #pragma unroll
    for (int k = 1; k < 8; ++k) mx = fmaxf(mx, u[k]);
    float e[8]; float s = 0.f;
    #pragma unroll
    for (int k = 0; k < 8; ++k) { e[k] = expf(u[k] - mx); s += e[k]; }
    float inv = 1.f / s;
    c[0] = -3.f;
    float cum = 0.f;
    #pragma unroll
    for (int k = 0; k < 8; ++k) {
        float v = 0.001f + 0.992f * e[k] * inv;
        cum += v;
        c[k + 1] = cum * 6.f - 3.f;
    }
    c[8] = 3.f;
    #pragma unroll
    for (int k = 0; k < 8; ++k) w[k] = c[k + 1] - c[k];
}

__device__ __forceinline__ void rqs1(float x,
                                     const float* __restrict__ uw,
                                     const float* __restrict__ uh,
                                     const float* __restrict__ ud,
                                     float& y, float& ld) {
    float cw[9], wd[8], ch[9], hg[8], dd[9];
    knots8(uw, cw, wd);
    knots8(uh, ch, hg);
    dd[0] = 1.f; dd[8] = 1.f;
    #pragma unroll
    for (int k = 0; k < 7; ++k) dd[k + 1] = 0.001f + softplusf(ud[k]);
    bool inside = (x >= -3.f) && (x <= 3.f);
    float xc = fminf(fmaxf(x, -3.f), 3.f);
    float cwk = cw[0], wk = wd[0], chk = ch[0], hk = hg[0], d0 = dd[0], d1 = dd[1];
    #pragma unroll
    for (int k = 1; k < 8; ++k) {
        if (xc >= cw[k]) { cwk = cw[k]; wk = wd[k]; chk = ch[k]; hk = hg[k]; d0 = dd[k]; d1 = dd[k + 1]; }
    }
    float dl = hk / wk;
    float th = (xc - cwk) / wk;
    float t1 = th * (1.f - th);
    float den = dl + (d0 + d1 - 2.f * dl) * t1;
    float yy = chk + hk * (dl * th * th + d0 * t1) / den;
    float om = 1.f - th;
    float dnum = dl * dl * (d1 * th * th + 2.f * dl * t1 + d0 * om * om);
    float lld = logf(dnum) - 2.f * logf(den);
    y  = inside ? yy : x;
    ld = inside ? lld : 0.f;
}

__global__ __launch_bounds__(256) void spline_kernel(float* __restrict__ z,
                                                     const float* __restrict__ p,
                                                     const float* __restrict__ uw_id,
                                                     const float* __restrict__ uh_id,
                                                     const float* __restrict__ ud_id,
                                                     float* __restrict__ logq) {
    int e = blockIdx.x * 256 + threadIdx.x;
    if (e >= NROWS * 8) return;
    int dim = e & 7;
    int row = e >> 3;
    float zid = z[(size_t)row * 16 + 2 * dim];
    float ztr = z[(size_t)row * 16 + 2 * dim + 1];
    const float* pr = p + (size_t)row * 184 + dim * 23;
    const float inv_sqrt_h = 0.08838834764831845f;  // 1/sqrt(128)
    float uw[8], uh[8], ud[7];
    #pragma unroll
    for (int k = 0; k < 8; ++k) { uw[k] = pr[k] * inv_sqrt_h; uh[k] = pr[8 + k] * inv_sqrt_h; }
    #pragma unroll
    for (int k = 0; k < 7; ++k) ud[k] = pr[16 + k];
    float ytr, ldtr; rqs1(ztr, uw, uh, ud, ytr, ldtr);
    float yid, ldid; rqs1(zid, uw_id + dim * 8, uh_id + dim * 8, ud_id + dim * 7, yid, ldid);
    z[(size_t)row * 16 + 2 * dim]     = yid;
    z[(size_t)row * 16 + 2 * dim + 1] = ytr;
    float ld = ldtr + ldid;
    ld += __shfl_xor(ld, 1);
    ld += __shfl_xor(ld, 2);
    ld += __shfl_xor(ld, 4);
    if (dim == 0) logq[row] += ld;
}

// ---------------- MADE output: scale/shift z, accumulate log|scale| ----------------
__global__ __launch_bounds__(256) void made_out_kernel(const float* __restrict__ ar,
                                                       float* __restrict__ z,
                                                       float* __restrict__ logq) {
    int row = blockIdx.x * 256 + threadIdx.x;
    if (row >= NROWS) return;
    const float* a = ar + (size_t)row * 32;
    float* zr = z + (size_t)row * 16;
    float lacc = 0.f;
    #pragma unroll
    for (int d = 0; d < 16; ++d) {
        float s = softplusf(a[2 * d]) + 0.001f;
        zr[d] = s * zr[d] + a[2 * d + 1];
        lacc += logf(s);
    }
    logq[row] += lacc;
}

// ---------------- Gaussian head + output transpose ----------------
__global__ __launch_bounds__(256) void final_kernel(const float* __restrict__ z,
                                                    const float* __restrict__ ehw,
                                                    const float* __restrict__ logq,
                                                    float* __restrict__ out) {
    int row = blockIdx.x * 256 + threadIdx.x;
    if (row >= NROWS) return;
    int hw = row >> 2, b = row & 3;
    const float* e = ehw + (size_t)hw * 32;
    const float* zr = z + (size_t)row * 16;
    float lq = logq[row] - 14.703016531274762f;  // -0.5*16*log(2*pi)
    #pragma unroll
    for (int d = 0; d < 16; ++d) {
        float ls = e[16 + d];
        float diff = (zr[d] - e[d]) * expf(-ls);
        lq -= ls + 0.5f * diff * diff;
    }
    out[(size_t)b * NHW + hw] = lq;
}

extern "C" void kernel_launch(void* const* d_in, const int* in_sizes, int n_in,
                              void* d_out, int out_size, void* d_ws, size_t ws_size,
                              hipStream_t stream) {
    (void)in_sizes; (void)n_in; (void)out_size; (void)ws_size;
    const float* x         = (const float*)d_in[0];
    const float* made_W0   = (const float*)d_in[1];
    const float* made_b0   = (const float*)d_in[2];
    const float* made_ctxW = (const float*)d_in[3];
    const float* made_ctxb = (const float*)d_in[4];
    const float* made_bW1  = (const float*)d_in[5];
    const float* made_bb1  = (const float*)d_in[6];
    const float* made_bW2  = (const float*)d_in[7];
    const float* made_bb2  = (const float*)d_in[8];
    const float* made_bCW  = (const float*)d_in[9];
    const float* made_bCb  = (const float*)d_in[10];
    const float* made_Wout = (const float*)d_in[11];
    const float* made_bout = (const float*)d_in[12];
    const float* sp_Win    = (const float*)d_in[13];
    const float* sp_bin    = (const float*)d_in[14];
    const float* sp_bW1    = (const float*)d_in[15];
    const float* sp_bb1    = (const float*)d_in[16];
    const float* sp_bW2    = (const float*)d_in[17];
    const float* sp_bb2    = (const float*)d_in[18];
    const float* sp_bCW    = (const float*)d_in[19];
    const float* sp_bCb    = (const float*)d_in[20];
    const float* sp_Wout   = (const float*)d_in[21];
    const float* sp_bout   = (const float*)d_in[22];
    const float* sp_uw     = (const float*)d_in[23];
    const float* sp_uh     = (const float*)d_in[24];
    const float* sp_ud     = (const float*)d_in[25];
    const float* lu_lower  = (const float*)d_in[26];
    const float* lu_upper  = (const float*)d_in[27];
    const float* lu_udiag  = (const float*)d_in[28];
    const float* lu_bias   = (const float*)d_in[29];
    const int*   lu_perm   = (const int*)d_in[30];
    const float* enc_W1    = (const float*)d_in[31];
    const float* enc_b1    = (const float*)d_in[32];
    const float* enc_W2    = (const float*)d_in[33];
    const float* enc_b2    = (const float*)d_in[34];
    float* out = (float*)d_out;

    float* ws      = (float*)d_ws;
    float* ctx     = ws;                               // 9216*128
    float* ctxout  = ctx     + (size_t)NHW * 128;      // 9216*384
    float* z       = ctxout  + (size_t)NHW * 384;      // 36864*16
    float* logq    = z       + (size_t)NROWS * 16;     // 36864
    float* p       = logq    + NROWS;                  // 36864*184
    float* thw_enc = p       + (size_t)NROWS * 184;    // 9216*128
    float* ehw     = thw_enc + (size_t)NHW * 128;      // 9216*32
    float* fpw     = ehw     + (size_t)NHW * 32;       // 4*49152
    float* mpw     = fpw     + 4 * 49152;              // 49152
    float* fpb     = mpw     + 49152;                  // 4*384
    float* mpb     = fpb     + 4 * 384;                // 384
    f16*   fW1f    = (f16*)(mpb + 384);                // 8*16384 f16
    f16*   fW2f    = fW1f    + 8 * 16384;              // 8*16384
    f16*   mW1f    = fW2f    + 8 * 16384;              // 2*16384
    f16*   mW2f    = mW1f    + 2 * 16384;              // 2*16384
    f16*   fWoutf  = mW2f    + 2 * 16384;              // 4*24576
    f16*   mWoutf  = fWoutf  + 4 * 24576;              // 4096
    f16*   finf    = mWoutf  + 4096;                   // 4*4096
    f16*   minf    = finf    + 4 * 4096;               // 4096

    dim3 B(256);
    pack_kernel<<<dim3(768, 12), B, 0, stream>>>(
        sp_bW1, sp_bW2, made_bW1, made_bW2, sp_Wout, made_Wout, sp_Win, made_W0,
        sp_bCW, made_ctxW, made_bCW, sp_bin, sp_bCb, made_ctxb, made_b0, made_bCb,
        fW1f, fW2f, mW1f, mW2f, fWoutf, mWoutf, finf, minf, fpw, mpw, fpb, mpb);
    ctx_kernel<<<4608, B, 0, stream>>>(ctx);
    snorm_kernel<<<2304, B, 0, stream>>>(x, z);
    initlogq_kernel<<<144, B, 0, stream>>>(lu_udiag, logq);

    for (int i = 3; i >= 0; --i) {
        lu_kernel<<<144, B, 0, stream>>>(z, lu_lower + i * 256, lu_upper + i * 256,
                                         lu_udiag + i * 16, lu_bias + i * 16, lu_perm + i * 16);
        gemm_k<4><<<dim3(144, 6), B, 0, stream>>>(ctx, 128, fpw + (size_t)i * 49152, 128,
                                                  fpb + i * 384, ctxout, 384, NHW, 384, 128);
        mega_mfma<0><<<576, B, 0, stream>>>(z, ctxout, finf + (size_t)i * 4096,
                                            fW1f + (size_t)i * 32768, fW2f + (size_t)i * 32768,
                                            sp_bb1 + i * 256, sp_bb2 + i * 256,
                                            fWoutf + (size_t)i * 24576, sp_bout + i * 184, p);
        spline_kernel<<<1152, B, 0, stream>>>(z, p, sp_uw + i * 64, sp_uh + i * 64, sp_ud + i * 56, logq);
    }

    // ---- MADE ----
    gemm_k<4><<<dim3(144, 6), B, 0, stream>>>(ctx, 128, mpw, 128, mpb, ctxout, 384, NHW, 384, 128);
    mega_mfma<1><<<576, B, 0, stream>>>(z, ctxout, minf, mW1f, mW2f,
                                        made_bb1, made_bb2, mWoutf, made_bout, p);
    made_out_kernel<<<144, B, 0, stream>>>(p, z, logq);

    // ---- encoder (per-hw) ----
    gemm_k<2><<<dim3(144, 2), B, 0, stream>>>(ctx, 128, enc_W1, 128, enc_b1, thw_enc, 128, NHW, 128, 128);
    gemm_k<0><<<dim3(144, 1), B, 0, stream>>>(thw_enc, 128, enc_W2, 128, enc_b2, ehw, 32, NHW, 32, 128);
    final_kernel<<<144, B, 0, stream>>>(z, ehw, logq, out);
}

// Round 6
// 454.556 us; speedup vs baseline: 1.4020x; 1.4020x over previous
//
#include <hip/hip_runtime.h>
#include <math.h>

#define NHW   9216     // 96*96
#define NROWS 36864    // NHW*4

typedef _Float16 f16;
typedef _Float16 f16x8 __attribute__((ext_vector_type(8)));
typedef float    f32x4 __attribute__((ext_vector_type(4)));

__device__ __forceinline__ float softplusf(float x) {
    return fmaxf(x, 0.f) + log1pf(expf(-fabsf(x)));
}

// ---------------- positional encoding ctx[hw][128] ----------------
__global__ __launch_bounds__(256) void ctx_kernel(float* __restrict__ ctx) {
    int e = blockIdx.x * 256 + threadIdx.x;
    if (e >= NHW * 128) return;
    int c  = e & 127;
    int hw = e >> 7;
    int i = hw / 96, j = hw % 96;
    int pos = (c < 64) ? i : j;
    int cc = c & 63;
    int k = cc >> 1;
    float invf = powf(10000.f, -(float)k / 32.f);
    float v = (float)pos * invf;
    ctx[e] = (cc & 1) ? cosf(v) : sinf(v);
}

// ---------------- spatial_norm -> z[row][16], row = (i*96+j)*4+b ----------------
__global__ __launch_bounds__(256) void snorm_kernel(const float* __restrict__ x,
                                                    float* __restrict__ z) {
    int e = blockIdx.x * 256 + threadIdx.x;
    if (e >= NROWS * 16) return;
    int j = e % 96;
    int i = (e / 96) % 96;
    int s = (e / 9216) % 16;
    int b = e / (9216 * 16);
    float sum = 0.f;
    const float* xb = x + (size_t)((b * 16 + s) * 3) * 192 * 192;
    #pragma unroll
    for (int c = 0; c < 3; ++c) {
        const float* xc = xb + (size_t)c * 192 * 192;
        #pragma unroll
        for (int dh = -1; dh <= 1; ++dh) {
            int hh = 2 * i + dh;
            if (hh < 0 || hh >= 192) continue;
            const float* xr = xc + hh * 192;
            #pragma unroll
            for (int dw = -1; dw <= 1; ++dw) {
                int ww = 2 * j + dw;
                if (ww < 0 || ww >= 192) continue;
                float v = xr[ww];
                sum += v * v;
            }
        }
    }
    int row = (i * 96 + j) * 4 + b;
    z[(size_t)row * 16 + s] = sqrtf(sum);
}

// ---------------- init logq with sum of LU log-dets (constant) ----------------
__global__ __launch_bounds__(256) void initlogq_kernel(const float* __restrict__ lu_udiag,
                                                       float* __restrict__ logq) {
    int row = blockIdx.x * 256 + threadIdx.x;
    if (row >= NROWS) return;
    float c0 = 0.f;
    for (int k = 0; k < 64; ++k)
        c0 += logf(softplusf(lu_udiag[k]) + 0.001f);
    logq[row] = c0;
}

// ---------------- LU transform: z = L(U z_perm) + bias (in place per row) ----------------
__global__ __launch_bounds__(256) void lu_kernel(float* __restrict__ z,
                                                 const float* __restrict__ lower,
                                                 const float* __restrict__ upper,
                                                 const float* __restrict__ udiag_raw,
                                                 const float* __restrict__ bias,
                                                 const int* __restrict__ perm) {
    int row = blockIdx.x * 256 + threadIdx.x;
    if (row >= NROWS) return;
    float* zr = z + (size_t)row * 16;
    float zp[16], y[16];
    #pragma unroll
    for (int d = 0; d < 16; ++d) zp[d] = zr[perm[d]];
    #pragma unroll
    for (int r = 0; r < 16; ++r) {
        float acc = (softplusf(udiag_raw[r]) + 0.001f) * zp[r];
        #pragma unroll
        for (int c = 0; c < 16; ++c)
            if (c > r) acc += upper[r * 16 + c] * zp[c];
        y[r] = acc;
    }
    #pragma unroll
    for (int r = 0; r < 16; ++r) {
        float acc = y[r] + bias[r];
        #pragma unroll
        for (int c = 0; c < 16; ++c)
            if (c < r) acc += lower[r * 16 + c] * y[c];
        zr[r] = acc;
    }
}

// ---------------- one-time weight pack kernel ----------------
// MFMA B-fragment order for a [N][K] weight (K=128): frag element
//   f = ((nt*4+ks)*64 + l)*8 + j  ->  n = nt*16+(l&15), k = ks*32+((l>>4)&3)*8+j
__global__ __launch_bounds__(256) void pack_kernel(
    const float* __restrict__ sp_bW1, const float* __restrict__ sp_bW2,
    const float* __restrict__ made_bW1, const float* __restrict__ made_bW2,
    const float* __restrict__ sp_Wout, const float* __restrict__ made_Wout,
    const float* __restrict__ sp_Win, const float* __restrict__ made_W0,
    const float* __restrict__ sp_bCW, const float* __restrict__ made_ctxW,
    const float* __restrict__ made_bCW,
    const float* __restrict__ sp_bin, const float* __restrict__ sp_bCb,
    const float* __restrict__ made_ctxb, const float* __restrict__ made_b0,
    const float* __restrict__ made_bCb,
    f16* __restrict__ fW1f, f16* __restrict__ fW2f,
    f16* __restrict__ mW1f, f16* __restrict__ mW2f,
    f16* __restrict__ fWoutf, f16* __restrict__ mWoutf,
    f16* __restrict__ finf, f16* __restrict__ minf,
    float* __restrict__ fpw, float* __restrict__ mpw,
    float* __restrict__ fpb, float* __restrict__ mpb)
{
    int cat = blockIdx.y;
    int e = blockIdx.x * 256 + threadIdx.x;
    switch (cat) {
    case 0: if (e < 8 * 16384) {
        int mtx = e >> 14, f = e & 16383;
        int nt = f >> 11, ks = (f >> 9) & 3, l = (f >> 3) & 63, j = f & 7;
        int n = nt * 16 + (l & 15), k = ks * 32 + ((l >> 4) & 3) * 8 + j;
        fW1f[e] = (f16)sp_bW1[mtx * 16384 + n * 128 + k];
    } break;
    case 1: if (e < 8 * 16384) {
        int mtx = e >> 14, f = e & 16383;
        int nt = f >> 11, ks = (f >> 9) & 3, l = (f >> 3) & 63, j = f & 7;
        int n = nt * 16 + (l & 15), k = ks * 32 + ((l >> 4) & 3) * 8 + j;
        fW2f[e] = (f16)sp_bW2[mtx * 16384 + n * 128 + k];
    } break;
    case 2: if (e < 2 * 16384) {
        int mtx = e >> 14, f = e & 16383;
        int nt = f >> 11, ks = (f >> 9) & 3, l = (f >> 3) & 63, j = f & 7;
        int n = nt * 16 + (l & 15), k = ks * 32 + ((l >> 4) & 3) * 8 + j;
        mW1f[e] = ((n % 15) >= (k % 15)) ? (f16)made_bW1[mtx * 16384 + n * 128 + k] : (f16)0.f;
    } break;
    case 3: if (e < 2 * 16384) {
        int mtx = e >> 14, f = e & 16383;
        int nt = f >> 11, ks = (f >> 9) & 3, l = (f >> 3) & 63, j = f & 7;
        int n = nt * 16 + (l & 15), k = ks * 32 + ((l >> 4) & 3) * 8 + j;
        mW2f[e] = ((n % 15) >= (k % 15)) ? (f16)made_bW2[mtx * 16384 + n * 128 + k] : (f16)0.f;
    } break;
    case 4: if (e < 4 * 24576) {
        int s = e / 24576, f = e % 24576;
        int nt = f >> 11, ks = (f >> 9) & 3, l = (f >> 3) & 63, j = f & 7;
        int n = nt * 16 + (l & 15), k = ks * 32 + ((l >> 4) & 3) * 8 + j;
        fWoutf[e] = (n < 184) ? (f16)sp_Wout[s * 23552 + n * 128 + k] : (f16)0.f;
    } break;
    case 5: if (e < 4096) {
        int f = e;
        int nt = f >> 11, ks = (f >> 9) & 3, l = (f >> 3) & 63, j = f & 7;
        int n = nt * 16 + (l & 15), k = ks * 32 + ((l >> 4) & 3) * 8 + j;
        mWoutf[e] = (((n & 15) > (k % 15)) && n < 32) ? (f16)made_Wout[n * 128 + k] : (f16)0.f;
    } break;
    case 6: if (e < 4 * 4096) {
        int s = e >> 12, f = e & 4095;
        int nt = f >> 9, l = (f >> 3) & 63, j = f & 7;
        int n = nt * 16 + (l & 15), k = ((l >> 4) & 3) * 8 + j;
        finf[e] = (k < 8) ? (f16)sp_Win[s * 17408 + n * 136 + k] : (f16)0.f;
    } break;
    case 7: if (e < 4096) {
        int f = e;
        int nt = f >> 9, l = (f >> 3) & 63, j = f & 7;
        int n = nt * 16 + (l & 15), k = ((l >> 4) & 3) * 8 + j;
        minf[e] = (k < 16 && (n % 15) >= k) ? (f16)made_W0[n * 16 + k] : (f16)0.f;
    } break;
    case 8: if (e < 4 * 49152) {
        int s = e / 49152, r = e % 49152, n = r >> 7, k = r & 127;
        float v;
        if (n < 128)      v = sp_Win[s * 17408 + n * 136 + 8 + k];
        else if (n < 256) v = sp_bCW[(size_t)(s * 2 + 0) * 16384 + (n - 128) * 128 + k];
        else              v = sp_bCW[(size_t)(s * 2 + 1) * 16384 + (n - 256) * 128 + k];
        fpw[e] = v;
    } break;
    case 9: if (e < 49152) {
        int n = e >> 7, k = e & 127;
        float v;
        if (n < 128)      v = made_ctxW[n * 128 + k];
        else if (n < 256) v = made_bCW[(n - 128) * 128 + k];
        else              v = made_bCW[16384 + (n - 256) * 128 + k];
        mpw[e] = v;
    } break;
    case 10: if (e < 4 * 384) {
        int s = e / 384, n = e % 384;
        float v;
        if (n < 128)      v = sp_bin[s * 128 + n];
        else if (n < 256) v = sp_bCb[(s * 2 + 0) * 128 + (n - 128)];
        else              v = sp_bCb[(s * 2 + 1) * 128 + (n - 256)];
        fpb[e] = v;
    } break;
    case 11: if (e < 384) {
        float v;
        if (e < 128)      v = made_ctxb[e] + made_b0[e];
        else if (e < 256) v = made_bCb[e - 128];
        else              v = made_bCb[128 + (e - 256)];
        mpb[e] = v;
    } break;
    }
}

// ---------------- tiled f32 GEMM (ctx / encoder): C = post(A @ W^T + bias) ----------------
// POST: 0 store, 2 silu, 4 mixed (n<128 store, else sigmoid)
template<int POST>
__global__ __launch_bounds__(256) void gemm_k(
    const float* __restrict__ A, int lda,
    const float* __restrict__ W, int ldw,
    const float* __restrict__ bias,
    float* __restrict__ C, int ldc,
    int M, int N, int K)
{
    __shared__ alignas(16) float As[16][68];
    __shared__ alignas(16) float Ws[16][68];
    const int tid = threadIdx.x;
    const int m0 = blockIdx.x * 64;
    const int n0 = blockIdx.y * 64;
    const int tm = (tid >> 4) << 2;
    const int tn = (tid & 15) << 2;
    const int srow = tid >> 2;
    const int skq  = (tid & 3) << 2;

    float acc[4][4] = {{0.f,0.f,0.f,0.f},{0.f,0.f,0.f,0.f},{0.f,0.f,0.f,0.f},{0.f,0.f,0.f,0.f}};

    for (int k0 = 0; k0 < K; k0 += 16) {
        float4 av = *(const float4*)(A + (size_t)(m0 + srow) * lda + k0 + skq);
        As[skq + 0][srow] = av.x; As[skq + 1][srow] = av.y;
        As[skq + 2][srow] = av.z; As[skq + 3][srow] = av.w;
        int wn = n0 + srow;
        float4 wv = make_float4(0.f, 0.f, 0.f, 0.f);
        if (wn < N) wv = *(const float4*)(W + (size_t)wn * ldw + k0 + skq);
        Ws[skq + 0][srow] = wv.x; Ws[skq + 1][srow] = wv.y;
        Ws[skq + 2][srow] = wv.z; Ws[skq + 3][srow] = wv.w;
        __syncthreads();
        #pragma unroll
        for (int kk = 0; kk < 16; ++kk) {
            float4 a4 = *(const float4*)&As[kk][tm];
            float4 w4 = *(const float4*)&Ws[kk][tn];
            float aa[4] = {a4.x, a4.y, a4.z, a4.w};
            float wwv[4] = {w4.x, w4.y, w4.z, w4.w};
            #pragma unroll
            for (int q = 0; q < 4; ++q)
                #pragma unroll
                for (int r = 0; r < 4; ++r)
                    acc[q][r] = fmaf(aa[q], wwv[r], acc[q][r]);
        }
        __syncthreads();
    }
    #pragma unroll
    for (int q = 0; q < 4; ++q) {
        int m = m0 + tm + q;
        #pragma unroll
        for (int r = 0; r < 4; ++r) {
            int n = n0 + tn + r;
            if (n < N) {
                float val = acc[q][r] + bias[n];
                float* cp = C + (size_t)m * ldc + n;
                if (POST == 0)      *cp = val;
                else if (POST == 2) *cp = val / (1.f + expf(-val));
                else                *cp = (n < 128) ? val : 1.f / (1.f + expf(-val));
            }
        }
    }
}

// ---------------- cooperative MFMA mega kernel ----------------
// block = 256 threads = 4 waves cooperating on ONE 16-row tile (2304 blocks).
// nt-groups split across waves: hidden stages 2/wave, Wout stride-4 (3/wave MODE0).
// 36 waves/CU requested -> 32 resident = 8/SIMD (vs 2.25 in the private-stripe form).
// Fragment maps (HW-verified rounds 4-5): A a[j]=src[l&15][ks*32+(l>>4)*8+j];
// B b[j]=W[nt*16+(l&15)][same k]; D row=(l>>4)*4+r, col=nt*16+(l&15).
template<int MODE>   // 0 flow (NOUT=184, even-z input), 1 made (NOUT=32, all-z input)
__global__ __launch_bounds__(256) void mega_mfma(
    const float* __restrict__ zg,       // [36864][16]
    const float* __restrict__ ctxout,   // [9216][384] thw | gate1 | gate2 (pre-sigmoided)
    const f16*  __restrict__ inf,       // [8*64*8] input-layer B-frags (K=32 pad)
    const f16*  __restrict__ W1f,       // [2][16384]
    const f16*  __restrict__ W2f,       // [2][16384]
    const float* __restrict__ bb1,      // [2][128]
    const float* __restrict__ bb2,      // [2][128]
    const f16*  __restrict__ Woutf,     // [NTO*2048]
    const float* __restrict__ boutv,    // [NOUT]
    float* __restrict__ p)              // [36864][NOUT]
{
    constexpr int NOUT = MODE ? 32 : 184;
    constexpr int NTO  = MODE ? 2 : 12;
    constexpr int NPT  = MODE ? 1 : 3;   // Wout nt per wave
    __shared__ alignas(16) f16 tS[16][136];
    __shared__ alignas(16) f16 uS[16][136];
    __shared__ alignas(16) f16 zS[16][32];
    const int tid = threadIdx.x;
    const int w   = tid >> 6;          // wave 0..3
    const int l   = tid & 63;
    const int m0  = blockIdx.x * 16;
    const int lr  = l & 15;
    const int lq  = l >> 4;
    const int hwq = (m0 >> 2) + lq;    // hw for this lane-quarter's 4 rows
    const int nt0 = w * 2;             // hidden-stage nt pair

    // ---- stage z tile: 256 threads, one element each ----
    {
        int r = tid >> 4, c = tid & 15;
        float v = zg[(size_t)(m0 + r) * 16 + c];
        if (MODE == 0) {
            zS[r][8 + c] = (f16)0.f;
            if (c < 8) zS[r][24 + c] = (f16)0.f;
            if ((c & 1) == 0) zS[r][c >> 1] = (f16)v;
        } else {
            zS[r][16 + c] = (f16)0.f;
            zS[r][c] = (f16)v;
        }
    }
    __syncthreads();

    const f32x4 vzero = {0.f, 0.f, 0.f, 0.f};

    // ---- input layer MFMA: t = thw + z_in @ Win_z (2 nt per wave) ----
    {
        f16x8 a = *(const f16x8*)&zS[lr][lq * 8];
        const float* cb = ctxout + (size_t)hwq * 384;
        #pragma unroll
        for (int t = 0; t < 2; ++t) {
            int nt = nt0 + t;
            float thw = cb[nt * 16 + lr];
            f32x4 c = {thw, thw, thw, thw};
            f16x8 b = *(const f16x8*)(inf + (nt * 64 + l) * 8);
            c = __builtin_amdgcn_mfma_f32_16x16x32_f16(a, b, c, 0, 0, 0);
            #pragma unroll
            for (int r = 0; r < 4; ++r)
                tS[lq * 4 + r][nt * 16 + lr] = (f16)c[r];
        }
    }
    __syncthreads();

    // ---- residual blocks (cooperative, 2 nt per wave) ----
    #pragma unroll
    for (int blk = 0; blk < 2; ++blk) {
        f32x4 acc[2];
        acc[0] = vzero; acc[1] = vzero;
        #pragma unroll
        for (int ks = 0; ks < 4; ++ks) {
            f16x8 a = *(const f16x8*)&tS[lr][ks * 32 + lq * 8];
            #pragma unroll
            for (int j = 0; j < 8; ++j) a[j] = a[j] > (f16)0.f ? a[j] : (f16)0.f;
            const f16* wb = W1f + (size_t)blk * 16384 + (ks * 64 + l) * 8;
            #pragma unroll
            for (int t = 0; t < 2; ++t) {
                f16x8 b = *(const f16x8*)(wb + (nt0 + t) * 2048);
                acc[t] = __builtin_amdgcn_mfma_f32_16x16x32_f16(a, b, acc[t], 0, 0, 0);
            }
        }
        #pragma unroll
        for (int t = 0; t < 2; ++t) {
            int nt = nt0 + t;
            float bias = bb1[blk * 128 + nt * 16 + lr];
            #pragma unroll
            for (int r = 0; r < 4; ++r)
                uS[lq * 4 + r][nt * 16 + lr] = (f16)(acc[t][r] + bias);
        }
        __syncthreads();

        acc[0] = vzero; acc[1] = vzero;
        #pragma unroll
        for (int ks = 0; ks < 4; ++ks) {
            f16x8 a = *(const f16x8*)&uS[lr][ks * 32 + lq * 8];
            #pragma unroll
            for (int j = 0; j < 8; ++j) a[j] = a[j] > (f16)0.f ? a[j] : (f16)0.f;
            const f16* wb = W2f + (size_t)blk * 16384 + (ks * 64 + l) * 8;
            #pragma unroll
            for (int t = 0; t < 2; ++t) {
                f16x8 b = *(const f16x8*)(wb + (nt0 + t) * 2048);
                acc[t] = __builtin_amdgcn_mfma_f32_16x16x32_f16(a, b, acc[t], 0, 0, 0);
            }
        }
        {
            const float* gb = ctxout + (size_t)hwq * 384 + 128 + blk * 128;
            #pragma unroll
            for (int t = 0; t < 2; ++t) {
                int nt = nt0 + t;
                float bias = bb2[blk * 128 + nt * 16 + lr];
                float g = gb[nt * 16 + lr];
                #pragma unroll
                for (int r = 0; r < 4; ++r) {
                    float tv = (float)tS[lq * 4 + r][nt * 16 + lr];
                    tS[lq * 4 + r][nt * 16 + lr] = (f16)(tv + (acc[t][r] + bias) * g);
                }
            }
        }
        __syncthreads();
    }

    // ---- output projection: p = t @ Wout + bout (nt = w, w+4, w+8...) ----
    if (MODE == 0 || w < NTO) {
        f32x4 po[NPT];
        #pragma unroll
        for (int q = 0; q < NPT; ++q) po[q] = vzero;
        #pragma unroll
        for (int ks = 0; ks < 4; ++ks) {
            f16x8 a = *(const f16x8*)&tS[lr][ks * 32 + lq * 8];
            const f16* wb = Woutf + (ks * 64 + l) * 8;
            #pragma unroll
            for (int q = 0; q < NPT; ++q) {
                int nt = w + q * 4;
                f16x8 b = *(const f16x8*)(wb + nt * 2048);
                po[q] = __builtin_amdgcn_mfma_f32_16x16x32_f16(a, b, po[q], 0, 0, 0);
            }
        }
        #pragma unroll
        for (int q = 0; q < NPT; ++q) {
            int nt = w + q * 4;
            int n = nt * 16 + lr;
            if (n < NOUT) {
                float bias = boutv[n];
                #pragma unroll
                for (int r = 0; r < 4; ++r) {
                    int gm = m0 + lq * 4 + r;
                    p[(size_t)gm * NOUT + n] = po[q][r] + bias;
                }
            }
        }
    }
}

// ---------------- rational-quadratic spline ----------------
__device__ __forceinline__ void knots8(const float* __restrict__ u, float* c, float* w) {
    float mx = u[0];
    #pragma unroll
    for (int k = 1; k < 8; ++k) mx = fmaxf(mx, u[k]);
    float e[8]; float s = 0.f;
    #pragma unroll
    for (int k = 0; k < 8; ++k) { e[k] = expf(u[k] - mx); s += e[k]; }
    float inv = 1.f / s;
    c[0] = -3.f;
    float cum = 0.f;
    #pragma unroll
    for (int k = 0; k < 8; ++k) {
        float v = 0.001f + 0.992f * e[k] * inv;
        cum += v;
        c[k + 1] = cum * 6.f - 3.f;
    }
    c[8] = 3.f;
    #pragma unroll
    for (int k = 0; k < 8; ++k) w[k] = c[k + 1] - c[k];
}

__device__ __forceinline__ void rqs1(float x,
                                     const float* __restrict__ uw,
                                     const float* __restrict__ uh,
                                     const float* __restrict__ ud,
                                     float& y, float& ld) {
    float cw[9], wd[8], ch[9], hg[8], dd[9];
    knots8(uw, cw, wd);
    knots8(uh, ch, hg);
    dd[0] = 1.f; dd[8] = 1.f;
    #pragma unroll
    for (int k = 0; k < 7; ++k) dd[k + 1] = 0.001f + softplusf(ud[k]);
    bool inside = (x >= -3.f) && (x <= 3.f);
    float xc = fminf(fmaxf(x, -3.f), 3.f);
    float cwk = cw[0], wk = wd[0], chk = ch[0], hk = hg[0], d0 = dd[0], d1 = dd[1];
    #pragma unroll
    for (int k = 1; k < 8; ++k) {
        if (xc >= cw[k]) { cwk = cw[k]; wk = wd[k]; chk = ch[k]; hk = hg[k]; d0 = dd[k]; d1 = dd[k + 1]; }
    }
    float dl = hk / wk;
    float th = (xc - cwk) / wk;
    float t1 = th * (1.f - th);
    float den = dl + (d0 + d1 - 2.f * dl) * t1;
    float yy = chk + hk * (dl * th * th + d0 * t1) / den;
    float om = 1.f - th;
    float dnum = dl * dl * (d1 * th * th + 2.f * dl * t1 + d0 * om * om);
    float lld = logf(dnum) - 2.f * logf(den);
    y  = inside ? yy : x;
    ld = inside ? lld : 0.f;
}

__global__ __launch_bounds__(256) void spline_kernel(float* __restrict__ z,
                                                     const float* __restrict__ p,
                                                     const float* __restrict__ uw_id,
                                                     const float* __restrict__ uh_id,
                                                     const float* __restrict__ ud_id,
                                                     float* __restrict__ logq) {
    int e = blockIdx.x * 256 + threadIdx.x;
    if (e >= NROWS * 8) return;
    int dim = e & 7;
    int row = e >> 3;
    float zid = z[(size_t)row * 16 + 2 * dim];
    float ztr = z[(size_t)row * 16 + 2 * dim + 1];
    const float* pr = p + (size_t)row * 184 + dim * 23;
    const float inv_sqrt_h = 0.08838834764831845f;  // 1/sqrt(128)
    float uw[8], uh[8], ud[7];
    #pragma unroll
    for (int k = 0; k < 8; ++k) { uw[k] = pr[k] * inv_sqrt_h; uh[k] = pr[8 + k] * inv_sqrt_h; }
    #pragma unroll
    for (int k = 0; k < 7; ++k) ud[k] = pr[16 + k];
    float ytr, ldtr; rqs1(ztr, uw, uh, ud, ytr, ldtr);
    float yid, ldid; rqs1(zid, uw_id + dim * 8, uh_id + dim * 8, ud_id + dim * 7, yid, ldid);
    z[(size_t)row * 16 + 2 * dim]     = yid;
    z[(size_t)row * 16 + 2 * dim + 1] = ytr;
    float ld = ldtr + ldid;
    ld += __shfl_xor(ld, 1);
    ld += __shfl_xor(ld, 2);
    ld += __shfl_xor(ld, 4);
    if (dim == 0) logq[row] += ld;
}

// ---------------- MADE output: scale/shift z, accumulate log|scale| ----------------
__global__ __launch_bounds__(256) void made_out_kernel(const float* __restrict__ ar,
                                                       float* __restrict__ z,
                                                       float* __restrict__ logq) {
    int row = blockIdx.x * 256 + threadIdx.x;
    if (row >= NROWS) return;
    const float* a = ar + (size_t)row * 32;
    float* zr = z + (size_t)row * 16;
    float lacc = 0.f;
    #pragma unroll
    for (int d = 0; d < 16; ++d) {
        float s = softplusf(a[2 * d]) + 0.001f;
        zr[d] = s * zr[d] + a[2 * d + 1];
        lacc += logf(s);
    }
    logq[row] += lacc;
}

// ---------------- Gaussian head + output transpose ----------------
__global__ __launch_bounds__(256) void final_kernel(const float* __restrict__ z,
                                                    const float* __restrict__ ehw,
                                                    const float* __restrict__ logq,
                                                    float* __restrict__ out) {
    int row = blockIdx.x * 256 + threadIdx.x;
    if (row >= NROWS) return;
    int hw = row >> 2, b = row & 3;
    const float* e = ehw + (size_t)hw * 32;
    const float* zr = z + (size_t)row * 16;
    float lq = logq[row] - 14.703016531274762f;  // -0.5*16*log(2*pi)
    #pragma unroll
    for (int d = 0; d < 16; ++d) {
        float ls = e[16 + d];
        float diff = (zr[d] - e[d]) * expf(-ls);
        lq -= ls + 0.5f * diff * diff;
    }
    out[(size_t)b * NHW + hw] = lq;
}

extern "C" void kernel_launch(void* const* d_in, const int* in_sizes, int n_in,
                              void* d_out, int out_size, void* d_ws, size_t ws_size,
                              hipStream_t stream) {
    (void)in_sizes; (void)n_in; (void)out_size; (void)ws_size;
    const float* x         = (const float*)d_in[0];
    const float* made_W0   = (const float*)d_in[1];
    const float* made_b0   = (const float*)d_in[2];
    const float* made_ctxW = (const float*)d_in[3];
    const float* made_ctxb = (const float*)d_in[4];
    const float* made_bW1  = (const float*)d_in[5];
    const float* made_bb1  = (const float*)d_in[6];
    const float* made_bW2  = (const float*)d_in[7];
    const float* made_bb2  = (const float*)d_in[8];
    const float* made_bCW  = (const float*)d_in[9];
    const float* made_bCb  = (const float*)d_in[10];
    const float* made_Wout = (const float*)d_in[11];
    const float* made_bout = (const float*)d_in[12];
    const float* sp_Win    = (const float*)d_in[13];
    const float* sp_bin    = (const float*)d_in[14];
    const float* sp_bW1    = (const float*)d_in[15];
    const float* sp_bb1    = (const float*)d_in[16];
    const float* sp_bW2    = (const float*)d_in[17];
    const float* sp_bb2    = (const float*)d_in[18];
    const float* sp_bCW    = (const float*)d_in[19];
    const float* sp_bCb    = (const float*)d_in[20];
    const float* sp_Wout   = (const float*)d_in[21];
    const float* sp_bout   = (const float*)d_in[22];
    const float* sp_uw     = (const float*)d_in[23];
    const float* sp_uh     = (const float*)d_in[24];
    const float* sp_ud     = (const float*)d_in[25];
    const float* lu_lower  = (const float*)d_in[26];
    const float* lu_upper  = (const float*)d_in[27];
    const float* lu_udiag  = (const float*)d_in[28];
    const float* lu_bias   = (const float*)d_in[29];
    const int*   lu_perm   = (const int*)d_in[30];
    const float* enc_W1    = (const float*)d_in[31];
    const float* enc_b1    = (const float*)d_in[32];
    const float* enc_W2    = (const float*)d_in[33];
    const float* enc_b2    = (const float*)d_in[34];
    float* out = (float*)d_out;

    float* ws      = (float*)d_ws;
    float* ctx     = ws;                               // 9216*128
    float* ctxout  = ctx     + (size_t)NHW * 128;      // 9216*384
    float* z       = ctxout  + (size_t)NHW * 384;      // 36864*16
    float* logq    = z       + (size_t)NROWS * 16;     // 36864
    float* p       = logq    + NROWS;                  // 36864*184
    float* thw_enc = p       + (size_t)NROWS * 184;    // 9216*128
    float* ehw     = thw_enc + (size_t)NHW * 128;      // 9216*32
    float* fpw     = ehw     + (size_t)NHW * 32;       // 4*49152
    float* mpw     = fpw     + 4 * 49152;              // 49152
    float* fpb     = mpw     + 49152;                  // 4*384
    float* mpb     = fpb     + 4 * 384;                // 384
    f16*   fW1f    = (f16*)(mpb + 384);                // 8*16384 f16
    f16*   fW2f    = fW1f    + 8 * 16384;              // 8*16384
    f16*   mW1f    = fW2f    + 8 * 16384;              // 2*16384
    f16*   mW2f    = mW1f    + 2 * 16384;              // 2*16384
    f16*   fWoutf  = mW2f    + 2 * 16384;              // 4*24576
    f16*   mWoutf  = fWoutf  + 4 * 24576;              // 4096
    f16*   finf    = mWoutf  + 4096;                   // 4*4096
    f16*   minf    = finf    + 4 * 4096;               // 4096

    dim3 B(256);
    pack_kernel<<<dim3(768, 12), B, 0, stream>>>(
        sp_bW1, sp_bW2, made_bW1, made_bW2, sp_Wout, made_Wout, sp_Win, made_W0,
        sp_bCW, made_ctxW, made_bCW, sp_bin, sp_bCb, made_ctxb, made_b0, made_bCb,
        fW1f, fW2f, mW1f, mW2f, fWoutf, mWoutf, finf, minf, fpw, mpw, fpb, mpb);
    ctx_kernel<<<4608, B, 0, stream>>>(ctx);
    snorm_kernel<<<2304, B, 0, stream>>>(x, z);
    initlogq_kernel<<<144, B, 0, stream>>>(lu_udiag, logq);

    for (int i = 3; i >= 0; --i) {
        lu_kernel<<<144, B, 0, stream>>>(z, lu_lower + i * 256, lu_upper + i * 256,
                                         lu_udiag + i * 16, lu_bias + i * 16, lu_perm + i * 16);
        gemm_k<4><<<dim3(144, 6), B, 0, stream>>>(ctx, 128, fpw + (size_t)i * 49152, 128,
                                                  fpb + i * 384, ctxout, 384, NHW, 384, 128);
        mega_mfma<0><<<2304, B, 0, stream>>>(z, ctxout, finf + (size_t)i * 4096,
                                             fW1f + (size_t)i * 32768, fW2f + (size_t)i * 32768,
                                             sp_bb1 + i * 256, sp_bb2 + i * 256,
                                             fWoutf + (size_t)i * 24576, sp_bout + i * 184, p);
        spline_kernel<<<1152, B, 0, stream>>>(z, p, sp_uw + i * 64, sp_uh + i * 64, sp_ud + i * 56, logq);
    }

    // ---- MADE ----
    gemm_k<4><<<dim3(144, 6), B, 0, stream>>>(ctx, 128, mpw, 128, mpb, ctxout, 384, NHW, 384, 128);
    mega_mfma<1><<<2304, B, 0, stream>>>(z, ctxout, minf, mW1f, mW2f,
                                         made_bb1, made_bb2, mWoutf, made_bout, p);
    made_out_kernel<<<144, B, 0, stream>>>(p, z, logq);

    // ---- encoder (per-hw) ----
    gemm_k<2><<<dim3(144, 2), B, 0, stream>>>(ctx, 128, enc_W1, 128, enc_b1, thw_enc, 128, NHW, 128, 128);
    gemm_k<0><<<dim3(144, 1), B, 0, stream>>>(thw_enc, 128, enc_W2, 128, enc_b2, ehw, 32, NHW, 32, 128);
    final_kernel<<<144, B, 0, stream>>>(z, ehw, logq, out);
}

// Round 7
// 352.430 us; speedup vs baseline: 1.8082x; 1.2898x over previous
//
#include <hip/hip_runtime.h>
#include <math.h>

#define NHW   9216     // 96*96
#define NROWS 36864    // NHW*4

typedef _Float16 f16;
typedef _Float16 f16x8 __attribute__((ext_vector_type(8)));
typedef float    f32x4 __attribute__((ext_vector_type(4)));

__device__ __forceinline__ float softplusf(float x) {
    return fmaxf(x, 0.f) + log1pf(expf(-fabsf(x)));
}

// ---------------- positional encoding ctx[hw][128] ----------------
__global__ __launch_bounds__(256) void ctx_kernel(float* __restrict__ ctx) {
    int e = blockIdx.x * 256 + threadIdx.x;
    if (e >= NHW * 128) return;
    int c  = e & 127;
    int hw = e >> 7;
    int i = hw / 96, j = hw % 96;
    int pos = (c < 64) ? i : j;
    int cc = c & 63;
    int k = cc >> 1;
    float invf = powf(10000.f, -(float)k / 32.f);
    float v = (float)pos * invf;
    ctx[e] = (cc & 1) ? cosf(v) : sinf(v);
}

// ---------------- spatial_norm -> z[row][16], row = (i*96+j)*4+b ----------------
__global__ __launch_bounds__(256) void snorm_kernel(const float* __restrict__ x,
                                                    float* __restrict__ z) {
    int e = blockIdx.x * 256 + threadIdx.x;
    if (e >= NROWS * 16) return;
    int j = e % 96;
    int i = (e / 96) % 96;
    int s = (e / 9216) % 16;
    int b = e / (9216 * 16);
    float sum = 0.f;
    const float* xb = x + (size_t)((b * 16 + s) * 3) * 192 * 192;
    #pragma unroll
    for (int c = 0; c < 3; ++c) {
        const float* xc = xb + (size_t)c * 192 * 192;
        #pragma unroll
        for (int dh = -1; dh <= 1; ++dh) {
            int hh = 2 * i + dh;
            if (hh < 0 || hh >= 192) continue;
            const float* xr = xc + hh * 192;
            #pragma unroll
            for (int dw = -1; dw <= 1; ++dw) {
                int ww = 2 * j + dw;
                if (ww < 0 || ww >= 192) continue;
                float v = xr[ww];
                sum += v * v;
            }
        }
    }
    int row = (i * 96 + j) * 4 + b;
    z[(size_t)row * 16 + s] = sqrtf(sum);
}

// ---------------- init logq with sum of LU log-dets (constant) ----------------
__global__ __launch_bounds__(256) void initlogq_kernel(const float* __restrict__ lu_udiag,
                                                       float* __restrict__ logq) {
    int row = blockIdx.x * 256 + threadIdx.x;
    if (row >= NROWS) return;
    float c0 = 0.f;
    for (int k = 0; k < 64; ++k)
        c0 += logf(softplusf(lu_udiag[k]) + 0.001f);
    logq[row] = c0;
}

// ---------------- LU transform: z = L(U z_perm) + bias (in place per row) ----------------
__global__ __launch_bounds__(256) void lu_kernel(float* __restrict__ z,
                                                 const float* __restrict__ lower,
                                                 const float* __restrict__ upper,
                                                 const float* __restrict__ udiag_raw,
                                                 const float* __restrict__ bias,
                                                 const int* __restrict__ perm) {
    int row = blockIdx.x * 256 + threadIdx.x;
    if (row >= NROWS) return;
    float* zr = z + (size_t)row * 16;
    float zp[16], y[16];
    #pragma unroll
    for (int d = 0; d < 16; ++d) zp[d] = zr[perm[d]];
    #pragma unroll
    for (int r = 0; r < 16; ++r) {
        float acc = (softplusf(udiag_raw[r]) + 0.001f) * zp[r];
        #pragma unroll
        for (int c = 0; c < 16; ++c)
            if (c > r) acc += upper[r * 16 + c] * zp[c];
        y[r] = acc;
    }
    #pragma unroll
    for (int r = 0; r < 16; ++r) {
        float acc = y[r] + bias[r];
        #pragma unroll
        for (int c = 0; c < 16; ++c)
            if (c < r) acc += lower[r * 16 + c] * y[c];
        zr[r] = acc;
    }
}

// ---------------- one-time weight pack kernel ----------------
// MFMA B-fragment order for a [N][K] weight (K=128): frag element
//   f = ((nt*4+ks)*64 + l)*8 + j  ->  n = nt*16+(l&15), k = ks*32+((l>>4)&3)*8+j
// cat 8: cfrag[5][24nt][4ks][64][8] f16 ctx-chain weights (s<4 flow, s=4 made)
// cat 9: cpb[5][384] f32 ctx-chain biases
__global__ __launch_bounds__(256) void pack_kernel(
    const float* __restrict__ sp_bW1, const float* __restrict__ sp_bW2,
    const float* __restrict__ made_bW1, const float* __restrict__ made_bW2,
    const float* __restrict__ sp_Wout, const float* __restrict__ made_Wout,
    const float* __restrict__ sp_Win, const float* __restrict__ made_W0,
    const float* __restrict__ sp_bCW, const float* __restrict__ made_ctxW,
    const float* __restrict__ made_bCW,
    const float* __restrict__ sp_bin, const float* __restrict__ sp_bCb,
    const float* __restrict__ made_ctxb, const float* __restrict__ made_b0,
    const float* __restrict__ made_bCb,
    f16* __restrict__ fW1f, f16* __restrict__ fW2f,
    f16* __restrict__ mW1f, f16* __restrict__ mW2f,
    f16* __restrict__ fWoutf, f16* __restrict__ mWoutf,
    f16* __restrict__ finf, f16* __restrict__ minf,
    f16* __restrict__ cfrag, float* __restrict__ cpb)
{
    int cat = blockIdx.y;
    int e = blockIdx.x * 256 + threadIdx.x;
    switch (cat) {
    case 0: if (e < 8 * 16384) {
        int mtx = e >> 14, f = e & 16383;
        int nt = f >> 11, ks = (f >> 9) & 3, l = (f >> 3) & 63, j = f & 7;
        int n = nt * 16 + (l & 15), k = ks * 32 + ((l >> 4) & 3) * 8 + j;
        fW1f[e] = (f16)sp_bW1[mtx * 16384 + n * 128 + k];
    } break;
    case 1: if (e < 8 * 16384) {
        int mtx = e >> 14, f = e & 16383;
        int nt = f >> 11, ks = (f >> 9) & 3, l = (f >> 3) & 63, j = f & 7;
        int n = nt * 16 + (l & 15), k = ks * 32 + ((l >> 4) & 3) * 8 + j;
        fW2f[e] = (f16)sp_bW2[mtx * 16384 + n * 128 + k];
    } break;
    case 2: if (e < 2 * 16384) {
        int mtx = e >> 14, f = e & 16383;
        int nt = f >> 11, ks = (f >> 9) & 3, l = (f >> 3) & 63, j = f & 7;
        int n = nt * 16 + (l & 15), k = ks * 32 + ((l >> 4) & 3) * 8 + j;
        mW1f[e] = ((n % 15) >= (k % 15)) ? (f16)made_bW1[mtx * 16384 + n * 128 + k] : (f16)0.f;
    } break;
    case 3: if (e < 2 * 16384) {
        int mtx = e >> 14, f = e & 16383;
        int nt = f >> 11, ks = (f >> 9) & 3, l = (f >> 3) & 63, j = f & 7;
        int n = nt * 16 + (l & 15), k = ks * 32 + ((l >> 4) & 3) * 8 + j;
        mW2f[e] = ((n % 15) >= (k % 15)) ? (f16)made_bW2[mtx * 16384 + n * 128 + k] : (f16)0.f;
    } break;
    case 4: if (e < 4 * 24576) {
        int s = e / 24576, f = e % 24576;
        int nt = f >> 11, ks = (f >> 9) & 3, l = (f >> 3) & 63, j = f & 7;
        int n = nt * 16 + (l & 15), k = ks * 32 + ((l >> 4) & 3) * 8 + j;
        fWoutf[e] = (n < 184) ? (f16)sp_Wout[s * 23552 + n * 128 + k] : (f16)0.f;
    } break;
    case 5: if (e < 4096) {
        int f = e;
        int nt = f >> 11, ks = (f >> 9) & 3, l = (f >> 3) & 63, j = f & 7;
        int n = nt * 16 + (l & 15), k = ks * 32 + ((l >> 4) & 3) * 8 + j;
        mWoutf[e] = (((n & 15) > (k % 15)) && n < 32) ? (f16)made_Wout[n * 128 + k] : (f16)0.f;
    } break;
    case 6: if (e < 4 * 4096) {
        int s = e >> 12, f = e & 4095;
        int nt = f >> 9, l = (f >> 3) & 63, j = f & 7;
        int n = nt * 16 + (l & 15), k = ((l >> 4) & 3) * 8 + j;
        finf[e] = (k < 8) ? (f16)sp_Win[s * 17408 + n * 136 + k] : (f16)0.f;
    } break;
    case 7: if (e < 4096) {
        int f = e;
        int nt = f >> 9, l = (f >> 3) & 63, j = f & 7;
        int n = nt * 16 + (l & 15), k = ((l >> 4) & 3) * 8 + j;
        minf[e] = (k < 16 && (n % 15) >= k) ? (f16)made_W0[n * 16 + k] : (f16)0.f;
    } break;
    case 8: if (e < 5 * 49152) {
        int s = e / 49152, f = e % 49152;
        int nt = f >> 11, ks = (f >> 9) & 3, l = (f >> 3) & 63, j = f & 7;
        int n = nt * 16 + (l & 15), k = ks * 32 + ((l >> 4) & 3) * 8 + j;
        float v;
        if (s < 4) {
            if (n < 128)      v = sp_Win[s * 17408 + n * 136 + 8 + k];
            else if (n < 256) v = sp_bCW[(size_t)(s * 2 + 0) * 16384 + (n - 128) * 128 + k];
            else              v = sp_bCW[(size_t)(s * 2 + 1) * 16384 + (n - 256) * 128 + k];
        } else {
            if (n < 128)      v = made_ctxW[n * 128 + k];
            else if (n < 256) v = made_bCW[(n - 128) * 128 + k];
            else              v = made_bCW[16384 + (n - 256) * 128 + k];
        }
        cfrag[e] = (f16)v;
    } break;
    case 9: if (e < 5 * 384) {
        int s = e / 384, n = e % 384;
        float v;
        if (s < 4) {
            if (n < 128)      v = sp_bin[s * 128 + n];
            else if (n < 256) v = sp_bCb[(s * 2 + 0) * 128 + (n - 128)];
            else              v = sp_bCb[(s * 2 + 1) * 128 + (n - 256)];
        } else {
            if (n < 128)      v = made_ctxb[n] + made_b0[n];
            else if (n < 256) v = made_bCb[n - 128];
            else              v = made_bCb[128 + (n - 256)];
        }
        cpb[e] = v;
    } break;
    }
}

// ---------------- ctx-chain MFMA: ctxoutf[s][hw][384] (n>=128 sigmoided), f16 ----------------
__global__ __launch_bounds__(256) void ctx_mfma(
    const float* __restrict__ ctx, const f16* __restrict__ cfrag,
    const float* __restrict__ cpb, f16* __restrict__ ctxoutf)
{
    __shared__ alignas(16) f16 cS[16][136];
    const int tid = threadIdx.x, w = tid >> 6, l = tid & 63;
    const int m0 = blockIdx.x * 16;
    const int s  = blockIdx.y;
    const int lr = l & 15, lq = l >> 4;
    #pragma unroll
    for (int it = 0; it < 2; ++it) {
        int e = tid + it * 256;
        int r = e >> 5, c4 = (e & 31) * 4;
        float4 v = *(const float4*)(ctx + (size_t)(m0 + r) * 128 + c4);
        cS[r][c4 + 0] = (f16)v.x; cS[r][c4 + 1] = (f16)v.y;
        cS[r][c4 + 2] = (f16)v.z; cS[r][c4 + 3] = (f16)v.w;
    }
    __syncthreads();
    const f32x4 vzero = {0.f, 0.f, 0.f, 0.f};
    f32x4 acc[6];
    #pragma unroll
    for (int q = 0; q < 6; ++q) acc[q] = vzero;
    const f16* wb = cfrag + (size_t)s * 49152;
    #pragma unroll
    for (int ks = 0; ks < 4; ++ks) {
        f16x8 a = *(const f16x8*)&cS[lr][ks * 32 + lq * 8];
        #pragma unroll
        for (int q = 0; q < 6; ++q) {
            int g = w * 6 + q;
            f16x8 b = *(const f16x8*)(wb + (size_t)((g * 4 + ks) * 64 + l) * 8);
            acc[q] = __builtin_amdgcn_mfma_f32_16x16x32_f16(a, b, acc[q], 0, 0, 0);
        }
    }
    #pragma unroll
    for (int q = 0; q < 6; ++q) {
        int g = w * 6 + q, n = g * 16 + lr;
        float bias = cpb[s * 384 + n];
        #pragma unroll
        for (int r = 0; r < 4; ++r) {
            float val = acc[q][r] + bias;
            if (n >= 128) val = 1.f / (1.f + expf(-val));
            ctxoutf[(size_t)s * NHW * 384 + (size_t)(m0 + lq * 4 + r) * 384 + n] = (f16)val;
        }
    }
}

// ---------------- tiled f32 GEMM (encoder): C = post(A @ W^T + bias) ----------------
template<int POST>   // 0 store, 2 silu
__global__ __launch_bounds__(256) void gemm_k(
    const float* __restrict__ A, int lda,
    const float* __restrict__ W, int ldw,
    const float* __restrict__ bias,
    float* __restrict__ C, int ldc,
    int M, int N, int K)
{
    __shared__ alignas(16) float As[16][68];
    __shared__ alignas(16) float Ws[16][68];
    const int tid = threadIdx.x;
    const int m0 = blockIdx.x * 64;
    const int n0 = blockIdx.y * 64;
    const int tm = (tid >> 4) << 2;
    const int tn = (tid & 15) << 2;
    const int srow = tid >> 2;
    const int skq  = (tid & 3) << 2;

    float acc[4][4] = {{0.f,0.f,0.f,0.f},{0.f,0.f,0.f,0.f},{0.f,0.f,0.f,0.f},{0.f,0.f,0.f,0.f}};

    for (int k0 = 0; k0 < K; k0 += 16) {
        float4 av = *(const float4*)(A + (size_t)(m0 + srow) * lda + k0 + skq);
        As[skq + 0][srow] = av.x; As[skq + 1][srow] = av.y;
        As[skq + 2][srow] = av.z; As[skq + 3][srow] = av.w;
        int wn = n0 + srow;
        float4 wv = make_float4(0.f, 0.f, 0.f, 0.f);
        if (wn < N) wv = *(const float4*)(W + (size_t)wn * ldw + k0 + skq);
        Ws[skq + 0][srow] = wv.x; Ws[skq + 1][srow] = wv.y;
        Ws[skq + 2][srow] = wv.z; Ws[skq + 3][srow] = wv.w;
        __syncthreads();
        #pragma unroll
        for (int kk = 0; kk < 16; ++kk) {
            float4 a4 = *(const float4*)&As[kk][tm];
            float4 w4 = *(const float4*)&Ws[kk][tn];
            float aa[4] = {a4.x, a4.y, a4.z, a4.w};
            float wwv[4] = {w4.x, w4.y, w4.z, w4.w};
            #pragma unroll
            for (int q = 0; q < 4; ++q)
                #pragma unroll
                for (int r = 0; r < 4; ++r)
                    acc[q][r] = fmaf(aa[q], wwv[r], acc[q][r]);
        }
        __syncthreads();
    }
    #pragma unroll
    for (int q = 0; q < 4; ++q) {
        int m = m0 + tm + q;
        #pragma unroll
        for (int r = 0; r < 4; ++r) {
            int n = n0 + tn + r;
            if (n < N) {
                float val = acc[q][r] + bias[n];
                float* cp = C + (size_t)m * ldc + n;
                if (POST == 0) *cp = val;
                else           *cp = val / (1.f + expf(-val));
            }
        }
    }
}

// ---------------- rational-quadratic spline ----------------
__device__ __forceinline__ void knots8(const float* __restrict__ u, float* c, float* w) {
    float mx = u[0];
    #pragma unroll
    for (int k = 1; k < 8; ++k) mx = fmaxf(mx, u[k]);
    float e[8]; float s = 0.f;
    #pragma unroll
    for (int k = 0; k < 8; ++k) { e[k] = expf(u[k] - mx); s += e[k]; }
    float inv = 1.f / s;
    c[0] = -3.f;
    float cum = 0.f;
    #pragma unroll
    for (int k = 0; k < 8; ++k) {
        float v = 0.001f + 0.992f * e[k] * inv;
        cum += v;
        c[k + 1] = cum * 6.f - 3.f;
    }
    c[8] = 3.f;
    #pragma unroll
    for (int k = 0; k < 8; ++k) w[k] = c[k + 1] - c[k];
}

__device__ __forceinline__ void rqs1(float x,
                                     const float* __restrict__ uw,
                                     const float* __restrict__ uh,
                                     const float* __restrict__ ud,
                                     float& y, float& ld) {
    float cw[9], wd[8], ch[9], hg[8], dd[9];
    knots8(uw, cw, wd);
    knots8(uh, ch, hg);
    dd[0] = 1.f; dd[8] = 1.f;
    #pragma unroll
    for (int k = 0; k < 7; ++k) dd[k + 1] = 0.001f + softplusf(ud[k]);
    bool inside = (x >= -3.f) && (x <= 3.f);
    float xc = fminf(fmaxf(x, -3.f), 3.f);
    float cwk = cw[0], wk = wd[0], chk = ch[0], hk = hg[0], d0 = dd[0], d1 = dd[1];
    #pragma unroll
    for (int k = 1; k < 8; ++k) {
        if (xc >= cw[k]) { cwk = cw[k]; wk = wd[k]; chk = ch[k]; hk = hg[k]; d0 = dd[k]; d1 = dd[k + 1]; }
    }
    float dl = hk / wk;
    float th = (xc - cwk) / wk;
    float t1 = th * (1.f - th);
    float den = dl + (d0 + d1 - 2.f * dl) * t1;
    float yy = chk + hk * (dl * th * th + d0 * t1) / den;
    float om = 1.f - th;
    float dnum = dl * dl * (d1 * th * th + 2.f * dl * t1 + d0 * om * om);
    float lld = logf(dnum) - 2.f * logf(den);
    y  = inside ? yy : x;
    ld = inside ? lld : 0.f;
}

// ---------------- cooperative MFMA mega kernel, fully fused ----------------
// block = 256 threads = 4 waves on ONE 16-row tile.
// MODE0: input + 2 res blocks + Wout -> LDS -> fused RQ-spline (updates z, logq).
// MODE1: input + 2 res blocks + Wout -> LDS -> fused MADE scale/shift + Gaussian head -> out.
template<int MODE>
__global__ __launch_bounds__(256) void mega_mfma(
    float* __restrict__ zg,             // [36864][16] (in/out for MODE0)
    const f16*  __restrict__ ctxoutf,   // [9216][384] f16 thw | gate1 | gate2
    const f16*  __restrict__ inf,       // [8*64*8] input-layer B-frags (K=32 pad)
    const f16*  __restrict__ W1f,       // [2][16384]
    const f16*  __restrict__ W2f,       // [2][16384]
    const float* __restrict__ bb1,      // [2][128]
    const float* __restrict__ bb2,      // [2][128]
    const f16*  __restrict__ Woutf,     // [NTO*2048]
    const float* __restrict__ boutv,    // [NOUT]
    const float* __restrict__ uw_id,    // MODE0: identity-spline params (8x8)
    const float* __restrict__ uh_id,
    const float* __restrict__ ud_id,    // (8x7)
    float* __restrict__ logq,           // [36864]
    const float* __restrict__ ehw,      // MODE1: [9216][32]
    float* __restrict__ out)            // MODE1: [4][9216]
{
    constexpr int NOUT = MODE ? 32 : 184;
    constexpr int NTO  = MODE ? 2 : 12;
    constexpr int NPT  = MODE ? 1 : 3;
    constexpr int PSC  = MODE ? 32 : 192;
    __shared__ alignas(16) f16 tS[16][136];
    __shared__ alignas(16) f16 uS[16][136];
    __shared__ alignas(16) f16 zS[16][32];
    __shared__ alignas(16) f16 pS[16][PSC];
    const int tid = threadIdx.x;
    const int w   = tid >> 6;
    const int l   = tid & 63;
    const int m0  = blockIdx.x * 16;
    const int lr  = l & 15;
    const int lq  = l >> 4;
    const int hwq = (m0 >> 2) + lq;
    const int nt0 = w * 2;

    // ---- stage z tile ----
    {
        int r = tid >> 4, c = tid & 15;
        float v = zg[(size_t)(m0 + r) * 16 + c];
        if (MODE == 0) {
            zS[r][8 + c] = (f16)0.f;
            if (c < 8) zS[r][24 + c] = (f16)0.f;
            if ((c & 1) == 0) zS[r][c >> 1] = (f16)v;
        } else {
            zS[r][16 + c] = (f16)0.f;
            zS[r][c] = (f16)v;
        }
    }
    __syncthreads();

    const f32x4 vzero = {0.f, 0.f, 0.f, 0.f};

    // ---- input layer MFMA: t = thw + z_in @ Win_z ----
    {
        f16x8 a = *(const f16x8*)&zS[lr][lq * 8];
        const f16* cb = ctxoutf + (size_t)hwq * 384;
        #pragma unroll
        for (int t = 0; t < 2; ++t) {
            int nt = nt0 + t;
            float thw = (float)cb[nt * 16 + lr];
            f32x4 c = {thw, thw, thw, thw};
            f16x8 b = *(const f16x8*)(inf + (nt * 64 + l) * 8);
            c = __builtin_amdgcn_mfma_f32_16x16x32_f16(a, b, c, 0, 0, 0);
            #pragma unroll
            for (int r = 0; r < 4; ++r)
                tS[lq * 4 + r][nt * 16 + lr] = (f16)c[r];
        }
    }
    __syncthreads();

    // ---- residual blocks ----
    #pragma unroll
    for (int blk = 0; blk < 2; ++blk) {
        f32x4 acc[2];
        acc[0] = vzero; acc[1] = vzero;
        #pragma unroll
        for (int ks = 0; ks < 4; ++ks) {
            f16x8 a = *(const f16x8*)&tS[lr][ks * 32 + lq * 8];
            #pragma unroll
            for (int j = 0; j < 8; ++j) a[j] = a[j] > (f16)0.f ? a[j] : (f16)0.f;
            const f16* wb = W1f + (size_t)blk * 16384 + (ks * 64 + l) * 8;
            #pragma unroll
            for (int t = 0; t < 2; ++t) {
                f16x8 b = *(const f16x8*)(wb + (nt0 + t) * 2048);
                acc[t] = __builtin_amdgcn_mfma_f32_16x16x32_f16(a, b, acc[t], 0, 0, 0);
            }
        }
        #pragma unroll
        for (int t = 0; t < 2; ++t) {
            int nt = nt0 + t;
            float bias = bb1[blk * 128 + nt * 16 + lr];
            #pragma unroll
            for (int r = 0; r < 4; ++r)
                uS[lq * 4 + r][nt * 16 + lr] = (f16)(acc[t][r] + bias);
        }
        __syncthreads();

        acc[0] = vzero; acc[1] = vzero;
        #pragma unroll
        for (int ks = 0; ks < 4; ++ks) {
            f16x8 a = *(const f16x8*)&uS[lr][ks * 32 + lq * 8];
            #pragma unroll
            for (int j = 0; j < 8; ++j) a[j] = a[j] > (f16)0.f ? a[j] : (f16)0.f;
            const f16* wb = W2f + (size_t)blk * 16384 + (ks * 64 + l) * 8;
            #pragma unroll
            for (int t = 0; t < 2; ++t) {
                f16x8 b = *(const f16x8*)(wb + (nt0 + t) * 2048);
                acc[t] = __builtin_amdgcn_mfma_f32_16x16x32_f16(a, b, acc[t], 0, 0, 0);
            }
        }
        {
            const f16* gb = ctxoutf + (size_t)hwq * 384 + 128 + blk * 128;
            #pragma unroll
            for (int t = 0; t < 2; ++t) {
                int nt = nt0 + t;
                float bias = bb2[blk * 128 + nt * 16 + lr];
                float g = (float)gb[nt * 16 + lr];
                #pragma unroll
                for (int r = 0; r < 4; ++r) {
                    float tv = (float)tS[lq * 4 + r][nt * 16 + lr];
                    tS[lq * 4 + r][nt * 16 + lr] = (f16)(tv + (acc[t][r] + bias) * g);
                }
            }
        }
        __syncthreads();
    }

    // ---- output projection -> pS (LDS) ----
    if (MODE == 0 || w < NTO) {
        f32x4 po[NPT];
        #pragma unroll
        for (int q = 0; q < NPT; ++q) po[q] = vzero;
        #pragma unroll
        for (int ks = 0; ks < 4; ++ks) {
            f16x8 a = *(const f16x8*)&tS[lr][ks * 32 + lq * 8];
            const f16* wb = Woutf + (ks * 64 + l) * 8;
            #pragma unroll
            for (int q = 0; q < NPT; ++q) {
                int nt = w + q * 4;
                f16x8 b = *(const f16x8*)(wb + nt * 2048);
                po[q] = __builtin_amdgcn_mfma_f32_16x16x32_f16(a, b, po[q], 0, 0, 0);
            }
        }
        #pragma unroll
        for (int q = 0; q < NPT; ++q) {
            int nt = w + q * 4;
            int n = nt * 16 + lr;
            if (n < NOUT) {
                float bias = boutv[n];
                #pragma unroll
                for (int r = 0; r < 4; ++r)
                    pS[lq * 4 + r][n] = (f16)(po[q][r] + bias);
            }
        }
    }
    __syncthreads();

    if (MODE == 0) {
        // ---- fused RQ-spline: 128 threads, one (row,dim) each ----
        if (tid < 128) {
            const int rw = tid >> 3, dim = tid & 7;
            const int gm = m0 + rw;
            const float inv_sqrt_h = 0.08838834764831845f;
            float uw[8], uh[8], ud[7];
            const f16* pr = &pS[rw][dim * 23];
            #pragma unroll
            for (int k = 0; k < 8; ++k) {
                uw[k] = (float)pr[k] * inv_sqrt_h;
                uh[k] = (float)pr[8 + k] * inv_sqrt_h;
            }
            #pragma unroll
            for (int k = 0; k < 7; ++k) ud[k] = (float)pr[16 + k];
            float zid = zg[(size_t)gm * 16 + 2 * dim];
            float ztr = zg[(size_t)gm * 16 + 2 * dim + 1];
            float ytr, ldtr; rqs1(ztr, uw, uh, ud, ytr, ldtr);
            float yid, ldid; rqs1(zid, uw_id + dim * 8, uh_id + dim * 8, ud_id + dim * 7, yid, ldid);
            zg[(size_t)gm * 16 + 2 * dim]     = yid;
            zg[(size_t)gm * 16 + 2 * dim + 1] = ytr;
            float ld = ldtr + ldid;
            ld += __shfl_xor(ld, 1);
            ld += __shfl_xor(ld, 2);
            ld += __shfl_xor(ld, 4);
            if (dim == 0) logq[gm] += ld;
        }
    } else {
        // ---- fused MADE scale/shift + Gaussian head: 256 threads, one (row,dim) ----
        const int rw = tid >> 4, d = tid & 15;
        const int gm = m0 + rw;
        const int hw = gm >> 2, b = gm & 3;
        float ar0 = (float)pS[rw][2 * d];
        float ar1 = (float)pS[rw][2 * d + 1];
        float s = softplusf(ar0) + 0.001f;
        float zn = s * zg[(size_t)gm * 16 + d] + ar1;
        float ls   = ehw[(size_t)hw * 32 + 16 + d];
        float mean = ehw[(size_t)hw * 32 + d];
        float diff = (zn - mean) * expf(-ls);
        float g = logf(s) - ls - 0.5f * diff * diff;
        g += __shfl_xor(g, 1);
        g += __shfl_xor(g, 2);
        g += __shfl_xor(g, 4);
        g += __shfl_xor(g, 8);
        if (d == 0)
            out[(size_t)b * NHW + hw] = logq[gm] + g - 14.703016531274762f;
    }
}

extern "C" void kernel_launch(void* const* d_in, const int* in_sizes, int n_in,
                              void* d_out, int out_size, void* d_ws, size_t ws_size,
                              hipStream_t stream) {
    (void)in_sizes; (void)n_in; (void)out_size; (void)ws_size;
    const float* x         = (const float*)d_in[0];
    const float* made_W0   = (const float*)d_in[1];
    const float* made_b0   = (const float*)d_in[2];
    const float* made_ctxW = (const float*)d_in[3];
    const float* made_ctxb = (const float*)d_in[4];
    const float* made_bW1  = (const float*)d_in[5];
    const float* made_bb1  = (const float*)d_in[6];
    const float* made_bW2  = (const float*)d_in[7];
    const float* made_bb2  = (const float*)d_in[8];
    const float* made_bCW  = (const float*)d_in[9];
    const float* made_bCb  = (const float*)d_in[10];
    const float* made_Wout = (const float*)d_in[11];
    const float* made_bout = (const float*)d_in[12];
    const float* sp_Win    = (const float*)d_in[13];
    const float* sp_bin    = (const float*)d_in[14];
    const float* sp_bW1    = (const float*)d_in[15];
    const float* sp_bb1    = (const float*)d_in[16];
    const float* sp_bW2    = (const float*)d_in[17];
    const float* sp_bb2    = (const float*)d_in[18];
    const float* sp_bCW    = (const float*)d_in[19];
    const float* sp_bCb    = (const float*)d_in[20];
    const float* sp_Wout   = (const float*)d_in[21];
    const float* sp_bout   = (const float*)d_in[22];
    const float* sp_uw     = (const float*)d_in[23];
    const float* sp_uh     = (const float*)d_in[24];
    const float* sp_ud     = (const float*)d_in[25];
    const float* lu_lower  = (const float*)d_in[26];
    const float* lu_upper  = (const float*)d_in[27];
    const float* lu_udiag  = (const float*)d_in[28];
    const float* lu_bias   = (const float*)d_in[29];
    const int*   lu_perm   = (const int*)d_in[30];
    const float* enc_W1    = (const float*)d_in[31];
    const float* enc_b1    = (const float*)d_in[32];
    const float* enc_W2    = (const float*)d_in[33];
    const float* enc_b2    = (const float*)d_in[34];
    float* out = (float*)d_out;

    float* ws      = (float*)d_ws;
    float* ctx     = ws;                               // 9216*128 f32
    float* z       = ctx     + (size_t)NHW * 128;      // 36864*16
    float* logq    = z       + (size_t)NROWS * 16;     // 36864
    float* thw_enc = logq    + NROWS;                  // 9216*128
    float* ehw     = thw_enc + (size_t)NHW * 128;      // 9216*32
    float* cpb     = ehw     + (size_t)NHW * 32;       // 5*384
    f16*   ctxoutf = (f16*)(cpb + 5 * 384);            // 5*9216*384 f16
    f16*   fW1f    = ctxoutf + (size_t)5 * NHW * 384;  // 8*16384
    f16*   fW2f    = fW1f    + 8 * 16384;              // 8*16384
    f16*   mW1f    = fW2f    + 8 * 16384;              // 2*16384
    f16*   mW2f    = mW1f    + 2 * 16384;              // 2*16384
    f16*   fWoutf  = mW2f    + 2 * 16384;              // 4*24576
    f16*   mWoutf  = fWoutf  + 4 * 24576;              // 4096
    f16*   finf    = mWoutf  + 4096;                   // 4*4096
    f16*   minf    = finf    + 4 * 4096;               // 4096
    f16*   cfrag   = minf    + 4096;                   // 5*49152

    dim3 B(256);
    pack_kernel<<<dim3(960, 10), B, 0, stream>>>(
        sp_bW1, sp_bW2, made_bW1, made_bW2, sp_Wout, made_Wout, sp_Win, made_W0,
        sp_bCW, made_ctxW, made_bCW, sp_bin, sp_bCb, made_ctxb, made_b0, made_bCb,
        fW1f, fW2f, mW1f, mW2f, fWoutf, mWoutf, finf, minf, cfrag, cpb);
    ctx_kernel<<<4608, B, 0, stream>>>(ctx);
    snorm_kernel<<<2304, B, 0, stream>>>(x, z);
    initlogq_kernel<<<144, B, 0, stream>>>(lu_udiag, logq);

    // all ctx-dependent precomputes
    ctx_mfma<<<dim3(576, 5), B, 0, stream>>>(ctx, cfrag, cpb, ctxoutf);
    gemm_k<2><<<dim3(144, 2), B, 0, stream>>>(ctx, 128, enc_W1, 128, enc_b1, thw_enc, 128, NHW, 128, 128);
    gemm_k<0><<<dim3(144, 1), B, 0, stream>>>(thw_enc, 128, enc_W2, 128, enc_b2, ehw, 32, NHW, 32, 128);

    for (int i = 3; i >= 0; --i) {
        lu_kernel<<<144, B, 0, stream>>>(z, lu_lower + i * 256, lu_upper + i * 256,
                                         lu_udiag + i * 16, lu_bias + i * 16, lu_perm + i * 16);
        mega_mfma<0><<<2304, B, 0, stream>>>(z, ctxoutf + (size_t)i * NHW * 384,
                                             finf + (size_t)i * 4096,
                                             fW1f + (size_t)i * 32768, fW2f + (size_t)i * 32768,
                                             sp_bb1 + i * 256, sp_bb2 + i * 256,
                                             fWoutf + (size_t)i * 24576, sp_bout + i * 184,
                                             sp_uw + i * 64, sp_uh + i * 64, sp_ud + i * 56,
                                             logq, nullptr, nullptr);
    }

    // ---- MADE + Gaussian head (fused) ----
    mega_mfma<1><<<2304, B, 0, stream>>>(z, ctxoutf + (size_t)4 * NHW * 384, minf, mW1f, mW2f,
                                         made_bb1, made_bb2, mWoutf, made_bout,
                                         nullptr, nullptr, nullptr,
                                         logq, ehw, out);
}

// Round 8
// 350.717 us; speedup vs baseline: 1.8170x; 1.0049x over previous
//
#include <hip/hip_runtime.h>
#include <math.h>

#define NHW   9216     // 96*96
#define NROWS 36864    // NHW*4

typedef _Float16 f16;
typedef _Float16 f16x8 __attribute__((ext_vector_type(8)));
typedef float    f32x4 __attribute__((ext_vector_type(4)));

__device__ __forceinline__ float softplusf(float x) {
    return fmaxf(x, 0.f) + log1pf(expf(-fabsf(x)));
}

// ---------------- positional encoding ctx[hw][128] ----------------
__global__ __launch_bounds__(256) void ctx_kernel(float* __restrict__ ctx) {
    int e = blockIdx.x * 256 + threadIdx.x;
    if (e >= NHW * 128) return;
    int c  = e & 127;
    int hw = e >> 7;
    int i = hw / 96, j = hw % 96;
    int pos = (c < 64) ? i : j;
    int cc = c & 63;
    int k = cc >> 1;
    float invf = powf(10000.f, -(float)k / 32.f);
    float v = (float)pos * invf;
    ctx[e] = (cc & 1) ? cosf(v) : sinf(v);
}

// ---------------- spatial_norm -> z[row][16], row = (i*96+j)*4+b ----------------
__global__ __launch_bounds__(256) void snorm_kernel(const float* __restrict__ x,
                                                    float* __restrict__ z) {
    int e = blockIdx.x * 256 + threadIdx.x;
    if (e >= NROWS * 16) return;
    int j = e % 96;
    int i = (e / 96) % 96;
    int s = (e / 9216) % 16;
    int b = e / (9216 * 16);
    float sum = 0.f;
    const float* xb = x + (size_t)((b * 16 + s) * 3) * 192 * 192;
    #pragma unroll
    for (int c = 0; c < 3; ++c) {
        const float* xc = xb + (size_t)c * 192 * 192;
        #pragma unroll
        for (int dh = -1; dh <= 1; ++dh) {
            int hh = 2 * i + dh;
            if (hh < 0 || hh >= 192) continue;
            const float* xr = xc + hh * 192;
            #pragma unroll
            for (int dw = -1; dw <= 1; ++dw) {
                int ww = 2 * j + dw;
                if (ww < 0 || ww >= 192) continue;
                float v = xr[ww];
                sum += v * v;
            }
        }
    }
    int row = (i * 96 + j) * 4 + b;
    z[(size_t)row * 16 + s] = sqrtf(sum);
}

// ---------------- init logq with sum of LU log-dets (constant) ----------------
__global__ __launch_bounds__(256) void initlogq_kernel(const float* __restrict__ lu_udiag,
                                                       float* __restrict__ logq) {
    int row = blockIdx.x * 256 + threadIdx.x;
    if (row >= NROWS) return;
    float c0 = 0.f;
    for (int k = 0; k < 64; ++k)
        c0 += logf(softplusf(lu_udiag[k]) + 0.001f);
    logq[row] = c0;
}

// ---------------- knots helper ----------------
__device__ __forceinline__ void knots8(const float* __restrict__ u, float* c, float* w) {
    float mx = u[0];
    #pragma unroll
    for (int k = 1; k < 8; ++k) mx = fmaxf(mx, u[k]);
    float e[8]; float s = 0.f;
    #pragma unroll
    for (int k = 0; k < 8; ++k) { e[k] = expf(u[k] - mx); s += e[k]; }
    float inv = 1.f / s;
    c[0] = -3.f;
    float cum = 0.f;
    #pragma unroll
    for (int k = 0; k < 8; ++k) {
        float v = 0.001f + 0.992f * e[k] * inv;
        cum += v;
        c[k + 1] = cum * 6.f - 3.f;
    }
    c[8] = 3.f;
    #pragma unroll
    for (int k = 0; k < 8; ++k) w[k] = c[k + 1] - c[k];
}

// ---------------- precompute identity-spline knots: idk[4][8][48] ----------------
// layout per (s,dim): cw[0..8], wd[9..16], ch[17..25], hg[26..33], dd[34..42]
__global__ __launch_bounds__(64) void idknots_kernel(const float* __restrict__ sp_uw,
                                                     const float* __restrict__ sp_uh,
                                                     const float* __restrict__ sp_ud,
                                                     float* __restrict__ idk) {
    int t = threadIdx.x;
    if (t >= 32) return;
    int s = t >> 3, dim = t & 7;
    float* o = idk + (s * 8 + dim) * 48;
    float c[9], w[8];
    knots8(sp_uw + s * 64 + dim * 8, c, w);
    #pragma unroll
    for (int k = 0; k < 9; ++k) o[k] = c[k];
    #pragma unroll
    for (int k = 0; k < 8; ++k) o[9 + k] = w[k];
    knots8(sp_uh + s * 64 + dim * 8, c, w);
    #pragma unroll
    for (int k = 0; k < 9; ++k) o[17 + k] = c[k];
    #pragma unroll
    for (int k = 0; k < 8; ++k) o[26 + k] = w[k];
    o[34] = 1.f; o[42] = 1.f;
    #pragma unroll
    for (int k = 0; k < 7; ++k) o[35 + k] = 0.001f + softplusf(sp_ud[s * 56 + dim * 7 + k]);
}

// ---------------- one-time weight pack kernel ----------------
// MFMA B-fragment order for a [N][K] weight (K=128): frag element
//   f = ((nt*4+ks)*64 + l)*8 + j  ->  n = nt*16+(l&15), k = ks*32+((l>>4)&3)*8+j
__global__ __launch_bounds__(256) void pack_kernel(
    const float* __restrict__ sp_bW1, const float* __restrict__ sp_bW2,
    const float* __restrict__ made_bW1, const float* __restrict__ made_bW2,
    const float* __restrict__ sp_Wout, const float* __restrict__ made_Wout,
    const float* __restrict__ sp_Win, const float* __restrict__ made_W0,
    const float* __restrict__ sp_bCW, const float* __restrict__ made_ctxW,
    const float* __restrict__ made_bCW,
    const float* __restrict__ sp_bin, const float* __restrict__ sp_bCb,
    const float* __restrict__ made_ctxb, const float* __restrict__ made_b0,
    const float* __restrict__ made_bCb,
    f16* __restrict__ fW1f, f16* __restrict__ fW2f,
    f16* __restrict__ mW1f, f16* __restrict__ mW2f,
    f16* __restrict__ fWoutf, f16* __restrict__ mWoutf,
    f16* __restrict__ finf, f16* __restrict__ minf,
    f16* __restrict__ cfrag, float* __restrict__ cpb)
{
    int cat = blockIdx.y;
    int e = blockIdx.x * 256 + threadIdx.x;
    switch (cat) {
    case 0: if (e < 8 * 16384) {
        int mtx = e >> 14, f = e & 16383;
        int nt = f >> 11, ks = (f >> 9) & 3, l = (f >> 3) & 63, j = f & 7;
        int n = nt * 16 + (l & 15), k = ks * 32 + ((l >> 4) & 3) * 8 + j;
        fW1f[e] = (f16)sp_bW1[mtx * 16384 + n * 128 + k];
    } break;
    case 1: if (e < 8 * 16384) {
        int mtx = e >> 14, f = e & 16383;
        int nt = f >> 11, ks = (f >> 9) & 3, l = (f >> 3) & 63, j = f & 7;
        int n = nt * 16 + (l & 15), k = ks * 32 + ((l >> 4) & 3) * 8 + j;
        fW2f[e] = (f16)sp_bW2[mtx * 16384 + n * 128 + k];
    } break;
    case 2: if (e < 2 * 16384) {
        int mtx = e >> 14, f = e & 16383;
        int nt = f >> 11, ks = (f >> 9) & 3, l = (f >> 3) & 63, j = f & 7;
        int n = nt * 16 + (l & 15), k = ks * 32 + ((l >> 4) & 3) * 8 + j;
        mW1f[e] = ((n % 15) >= (k % 15)) ? (f16)made_bW1[mtx * 16384 + n * 128 + k] : (f16)0.f;
    } break;
    case 3: if (e < 2 * 16384) {
        int mtx = e >> 14, f = e & 16383;
        int nt = f >> 11, ks = (f >> 9) & 3, l = (f >> 3) & 63, j = f & 7;
        int n = nt * 16 + (l & 15), k = ks * 32 + ((l >> 4) & 3) * 8 + j;
        mW2f[e] = ((n % 15) >= (k % 15)) ? (f16)made_bW2[mtx * 16384 + n * 128 + k] : (f16)0.f;
    } break;
    case 4: if (e < 4 * 24576) {
        int s = e / 24576, f = e % 24576;
        int nt = f >> 11, ks = (f >> 9) & 3, l = (f >> 3) & 63, j = f & 7;
        int n = nt * 16 + (l & 15), k = ks * 32 + ((l >> 4) & 3) * 8 + j;
        fWoutf[e] = (n < 184) ? (f16)sp_Wout[s * 23552 + n * 128 + k] : (f16)0.f;
    } break;
    case 5: if (e < 4096) {
        int f = e;
        int nt = f >> 11, ks = (f >> 9) & 3, l = (f >> 3) & 63, j = f & 7;
        int n = nt * 16 + (l & 15), k = ks * 32 + ((l >> 4) & 3) * 8 + j;
        mWoutf[e] = (((n & 15) > (k % 15)) && n < 32) ? (f16)made_Wout[n * 128 + k] : (f16)0.f;
    } break;
    case 6: if (e < 4 * 4096) {
        int s = e >> 12, f = e & 4095;
        int nt = f >> 9, l = (f >> 3) & 63, j = f & 7;
        int n = nt * 16 + (l & 15), k = ((l >> 4) & 3) * 8 + j;
        finf[e] = (k < 8) ? (f16)sp_Win[s * 17408 + n * 136 + k] : (f16)0.f;
    } break;
    case 7: if (e < 4096) {
        int f = e;
        int nt = f >> 9, l = (f >> 3) & 63, j = f & 7;
        int n = nt * 16 + (l & 15), k = ((l >> 4) & 3) * 8 + j;
        minf[e] = (k < 16 && (n % 15) >= k) ? (f16)made_W0[n * 16 + k] : (f16)0.f;
    } break;
    case 8: if (e < 5 * 49152) {
        int s = e / 49152, f = e % 49152;
        int nt = f >> 11, ks = (f >> 9) & 3, l = (f >> 3) & 63, j = f & 7;
        int n = nt * 16 + (l & 15), k = ks * 32 + ((l >> 4) & 3) * 8 + j;
        float v;
        if (s < 4) {
            if (n < 128)      v = sp_Win[s * 17408 + n * 136 + 8 + k];
            else if (n < 256) v = sp_bCW[(size_t)(s * 2 + 0) * 16384 + (n - 128) * 128 + k];
            else              v = sp_bCW[(size_t)(s * 2 + 1) * 16384 + (n - 256) * 128 + k];
        } else {
            if (n < 128)      v = made_ctxW[n * 128 + k];
            else if (n < 256) v = made_bCW[(n - 128) * 128 + k];
            else              v = made_bCW[16384 + (n - 256) * 128 + k];
        }
        cfrag[e] = (f16)v;
    } break;
    case 9: if (e < 5 * 384) {
        int s = e / 384, n = e % 384;
        float v;
        if (s < 4) {
            if (n < 128)      v = sp_bin[s * 128 + n];
            else if (n < 256) v = sp_bCb[(s * 2 + 0) * 128 + (n - 128)];
            else              v = sp_bCb[(s * 2 + 1) * 128 + (n - 256)];
        } else {
            if (n < 128)      v = made_ctxb[n] + made_b0[n];
            else if (n < 256) v = made_bCb[n - 128];
            else              v = made_bCb[128 + (n - 256)];
        }
        cpb[e] = v;
    } break;
    }
}

// ---------------- ctx-chain MFMA: ctxoutf[s][hw][384] (n>=128 sigmoided), f16 ----------------
__global__ __launch_bounds__(256) void ctx_mfma(
    const float* __restrict__ ctx, const f16* __restrict__ cfrag,
    const float* __restrict__ cpb, f16* __restrict__ ctxoutf)
{
    __shared__ alignas(16) f16 cS[16][136];
    const int tid = threadIdx.x, w = tid >> 6, l = tid & 63;
    const int m0 = blockIdx.x * 16;
    const int s  = blockIdx.y;
    const int lr = l & 15, lq = l >> 4;
    #pragma unroll
    for (int it = 0; it < 2; ++it) {
        int e = tid + it * 256;
        int r = e >> 5, c4 = (e & 31) * 4;
        float4 v = *(const float4*)(ctx + (size_t)(m0 + r) * 128 + c4);
        cS[r][c4 + 0] = (f16)v.x; cS[r][c4 + 1] = (f16)v.y;
        cS[r][c4 + 2] = (f16)v.z; cS[r][c4 + 3] = (f16)v.w;
    }
    __syncthreads();
    const f32x4 vzero = {0.f, 0.f, 0.f, 0.f};
    f32x4 acc[6];
    #pragma unroll
    for (int q = 0; q < 6; ++q) acc[q] = vzero;
    const f16* wb = cfrag + (size_t)s * 49152;
    #pragma unroll
    for (int ks = 0; ks < 4; ++ks) {
        f16x8 a = *(const f16x8*)&cS[lr][ks * 32 + lq * 8];
        #pragma unroll
        for (int q = 0; q < 6; ++q) {
            int g = w * 6 + q;
            f16x8 b = *(const f16x8*)(wb + (size_t)((g * 4 + ks) * 64 + l) * 8);
            acc[q] = __builtin_amdgcn_mfma_f32_16x16x32_f16(a, b, acc[q], 0, 0, 0);
        }
    }
    #pragma unroll
    for (int q = 0; q < 6; ++q) {
        int g = w * 6 + q, n = g * 16 + lr;
        float bias = cpb[s * 384 + n];
        #pragma unroll
        for (int r = 0; r < 4; ++r) {
            float val = acc[q][r] + bias;
            if (n >= 128) val = 1.f / (1.f + expf(-val));
            ctxoutf[(size_t)s * NHW * 384 + (size_t)(m0 + lq * 4 + r) * 384 + n] = (f16)val;
        }
    }
}

// ---------------- tiled f32 GEMM (encoder): C = post(A @ W^T + bias) ----------------
template<int POST>   // 0 store, 2 silu
__global__ __launch_bounds__(256) void gemm_k(
    const float* __restrict__ A, int lda,
    const float* __restrict__ W, int ldw,
    const float* __restrict__ bias,
    float* __restrict__ C, int ldc,
    int M, int N, int K)
{
    __shared__ alignas(16) float As[16][68];
    __shared__ alignas(16) float Ws[16][68];
    const int tid = threadIdx.x;
    const int m0 = blockIdx.x * 64;
    const int n0 = blockIdx.y * 64;
    const int tm = (tid >> 4) << 2;
    const int tn = (tid & 15) << 2;
    const int srow = tid >> 2;
    const int skq  = (tid & 3) << 2;

    float acc[4][4] = {{0.f,0.f,0.f,0.f},{0.f,0.f,0.f,0.f},{0.f,0.f,0.f,0.f},{0.f,0.f,0.f,0.f}};

    for (int k0 = 0; k0 < K; k0 += 16) {
        float4 av = *(const float4*)(A + (size_t)(m0 + srow) * lda + k0 + skq);
        As[skq + 0][srow] = av.x; As[skq + 1][srow] = av.y;
        As[skq + 2][srow] = av.z; As[skq + 3][srow] = av.w;
        int wn = n0 + srow;
        float4 wv = make_float4(0.f, 0.f, 0.f, 0.f);
        if (wn < N) wv = *(const float4*)(W + (size_t)wn * ldw + k0 + skq);
        Ws[skq + 0][srow] = wv.x; Ws[skq + 1][srow] = wv.y;
        Ws[skq + 2][srow] = wv.z; Ws[skq + 3][srow] = wv.w;
        __syncthreads();
        #pragma unroll
        for (int kk = 0; kk < 16; ++kk) {
            float4 a4 = *(const float4*)&As[kk][tm];
            float4 w4 = *(const float4*)&Ws[kk][tn];
            float aa[4] = {a4.x, a4.y, a4.z, a4.w};
            float wwv[4] = {w4.x, w4.y, w4.z, w4.w};
            #pragma unroll
            for (int q = 0; q < 4; ++q)
                #pragma unroll
                for (int r = 0; r < 4; ++r)
                    acc[q][r] = fmaf(aa[q], wwv[r], acc[q][r]);
        }
        __syncthreads();
    }
    #pragma unroll
    for (int q = 0; q < 4; ++q) {
        int m = m0 + tm + q;
        #pragma unroll
        for (int r = 0; r < 4; ++r) {
            int n = n0 + tn + r;
            if (n < N) {
                float val = acc[q][r] + bias[n];
                float* cp = C + (size_t)m * ldc + n;
                if (POST == 0) *cp = val;
                else           *cp = val / (1.f + expf(-val));
            }
        }
    }
}

// ---------------- rational-quadratic spline core ----------------
__device__ __forceinline__ void rqs_core(float x, const float* cw, const float* wd,
                                         const float* ch, const float* hg, const float* dd,
                                         float& y, float& ld) {
    bool inside = (x >= -3.f) && (x <= 3.f);
    float xc = fminf(fmaxf(x, -3.f), 3.f);
    float cwk = cw[0], wk = wd[0], chk = ch[0], hk = hg[0], d0 = dd[0], d1 = dd[1];
    #pragma unroll
    for (int k = 1; k < 8; ++k) {
        if (xc >= cw[k]) { cwk = cw[k]; wk = wd[k]; chk = ch[k]; hk = hg[k]; d0 = dd[k]; d1 = dd[k + 1]; }
    }
    float dl = hk / wk;
    float th = (xc - cwk) / wk;
    float t1 = th * (1.f - th);
    float den = dl + (d0 + d1 - 2.f * dl) * t1;
    float yy = chk + hk * (dl * th * th + d0 * t1) / den;
    float om = 1.f - th;
    float dnum = dl * dl * (d1 * th * th + 2.f * dl * t1 + d0 * om * om);
    float lld = logf(dnum) - 2.f * logf(den);
    y  = inside ? yy : x;
    ld = inside ? lld : 0.f;
}

__device__ __forceinline__ void rqs1(float x,
                                     const float* __restrict__ uw,
                                     const float* __restrict__ uh,
                                     const float* __restrict__ ud,
                                     float& y, float& ld) {
    float cw[9], wd[8], ch[9], hg[8], dd[9];
    knots8(uw, cw, wd);
    knots8(uh, ch, hg);
    dd[0] = 1.f; dd[8] = 1.f;
    #pragma unroll
    for (int k = 0; k < 7; ++k) dd[k + 1] = 0.001f + softplusf(ud[k]);
    rqs_core(x, cw, wd, ch, hg, dd, y, ld);
}

__device__ __forceinline__ void rqs1_pre(float x, const float* __restrict__ kn,
                                         float& y, float& ld) {
    float cw[9], wd[8], ch[9], hg[8], dd[9];
    #pragma unroll
    for (int k = 0; k < 9; ++k) cw[k] = kn[k];
    #pragma unroll
    for (int k = 0; k < 8; ++k) wd[k] = kn[9 + k];
    #pragma unroll
    for (int k = 0; k < 9; ++k) ch[k] = kn[17 + k];
    #pragma unroll
    for (int k = 0; k < 8; ++k) hg[k] = kn[26 + k];
    #pragma unroll
    for (int k = 0; k < 9; ++k) dd[k] = kn[34 + k];
    rqs_core(x, cw, wd, ch, hg, dd, y, ld);
}

// ---------------- cooperative MFMA mega kernel, fully fused ----------------
// block = 256 threads = 4 waves on ONE 16-row tile.
// MODE0: LU -> input + 2 res blocks + Wout -> fused RQ-spline (updates z, logq).
// MODE1: input + 2 res blocks + Wout -> MADE scale/shift + Gaussian head -> out.
// VALU diet: activations stored pre-relu'd; residual t kept in registers (tReg);
// spline tail wave-specialized (waves 0-1 tr full-lane, waves 2-3 id w/ precomputed knots).
template<int MODE>
__global__ __launch_bounds__(256) void mega_mfma(
    float* __restrict__ zg,             // [36864][16]
    const f16*  __restrict__ ctxoutf,   // [9216][384] f16 thw | gate1 | gate2
    const f16*  __restrict__ inf,       // input-layer B-frags (K=32 pad)
    const f16*  __restrict__ W1f,       // [2][16384]
    const f16*  __restrict__ W2f,       // [2][16384]
    const float* __restrict__ bb1,      // [2][128]
    const float* __restrict__ bb2,      // [2][128]
    const f16*  __restrict__ Woutf,     // [NTO*2048]
    const float* __restrict__ boutv,    // [NOUT]
    const float* __restrict__ lu_lower, // MODE0: [16][16]
    const float* __restrict__ lu_upper,
    const float* __restrict__ lu_udiag, // [16]
    const float* __restrict__ lu_bias,  // [16]
    const int*   __restrict__ lu_perm,  // [16]
    const float* __restrict__ idk,      // MODE0: [8][48] precomputed id-spline knots
    float* __restrict__ logq,           // [36864]
    const float* __restrict__ ehw,      // MODE1: [9216][32]
    float* __restrict__ out)            // MODE1: [4][9216]
{
    constexpr int NOUT = MODE ? 32 : 184;
    constexpr int NTO  = MODE ? 2 : 12;
    constexpr int NPT  = MODE ? 1 : 3;
    constexpr int PSC  = MODE ? 32 : 192;
    __shared__ alignas(16) f16 tS[16][136];
    __shared__ alignas(16) f16 uS[16][136];
    __shared__ alignas(16) f16 zS[16][32];
    __shared__ alignas(16) f16 pS[16][PSC];
    __shared__ float zF[16][16];   // MODE0: scratch (y) then logq-reduce
    __shared__ float zP[16][16];   // MODE0: post-LU z (f32)
    const int tid = threadIdx.x;
    const int w   = tid >> 6;
    const int l   = tid & 63;
    const int m0  = blockIdx.x * 16;
    const int lr  = l & 15;
    const int lq  = l >> 4;
    const int hwq = (m0 >> 2) + lq;
    const int nt0 = w * 2;

    if (MODE == 0) {
        // ---- fused LU: z = L(U z_perm) + bias, 16 threads per row ----
        const int r2 = tid >> 4, d2 = tid & 15;
        zF[r2][d2] = zg[(size_t)(m0 + r2) * 16 + d2];
        __syncthreads();
        float zp = zF[r2][lu_perm[d2]];
        zP[r2][d2] = zp;
        __syncthreads();
        float acc = (softplusf(lu_udiag[d2]) + 0.001f) * zp;
        #pragma unroll
        for (int c = 0; c < 16; ++c)
            if (c > d2) acc += lu_upper[d2 * 16 + c] * zP[r2][c];
        zF[r2][d2] = acc;   // y
        __syncthreads();
        float fin = acc + lu_bias[d2];
        #pragma unroll
        for (int c = 0; c < 16; ++c)
            if (c < d2) fin += lu_lower[d2 * 16 + c] * zF[r2][c];
        zP[r2][d2] = fin;
        // stage zS (even dims, K=32 pad)
        if (d2 < 12) { zS[r2][8 + d2] = (f16)0.f; zS[r2][20 + d2] = (f16)0.f; }
        if ((d2 & 1) == 0) zS[r2][d2 >> 1] = (f16)fin;
        __syncthreads();
    } else {
        const int r2 = tid >> 4, d2 = tid & 15;
        float v = zg[(size_t)(m0 + r2) * 16 + d2];
        zS[r2][16 + d2] = (f16)0.f;
        zS[r2][d2] = (f16)v;
        __syncthreads();
    }

    const f32x4 vzero = {0.f, 0.f, 0.f, 0.f};
    float tReg[2][4];

    // ---- input layer MFMA: t = thw + z_in @ Win_z; store relu(t) ----
    {
        f16x8 a = *(const f16x8*)&zS[lr][lq * 8];
        const f16* cb = ctxoutf + (size_t)hwq * 384;
        #pragma unroll
        for (int t = 0; t < 2; ++t) {
            int nt = nt0 + t;
            float thw = (float)cb[nt * 16 + lr];
            f32x4 c = {thw, thw, thw, thw};
            f16x8 b = *(const f16x8*)(inf + (nt * 64 + l) * 8);
            c = __builtin_amdgcn_mfma_f32_16x16x32_f16(a, b, c, 0, 0, 0);
            #pragma unroll
            for (int r = 0; r < 4; ++r) {
                tReg[t][r] = c[r];
                tS[lq * 4 + r][nt * 16 + lr] = (f16)fmaxf(c[r], 0.f);
            }
        }
    }
    __syncthreads();

    // ---- residual blocks (tS/uS hold relu'd activations; raw t in tReg) ----
    #pragma unroll
    for (int blk = 0; blk < 2; ++blk) {
        f32x4 acc[2];
        acc[0] = vzero; acc[1] = vzero;
        #pragma unroll
        for (int ks = 0; ks < 4; ++ks) {
            f16x8 a = *(const f16x8*)&tS[lr][ks * 32 + lq * 8];
            const f16* wb = W1f + (size_t)blk * 16384 + (ks * 64 + l) * 8;
            #pragma unroll
            for (int t = 0; t < 2; ++t) {
                f16x8 b = *(const f16x8*)(wb + (nt0 + t) * 2048);
                acc[t] = __builtin_amdgcn_mfma_f32_16x16x32_f16(a, b, acc[t], 0, 0, 0);
            }
        }
        #pragma unroll
        for (int t = 0; t < 2; ++t) {
            int nt = nt0 + t;
            float bias = bb1[blk * 128 + nt * 16 + lr];
            #pragma unroll
            for (int r = 0; r < 4; ++r)
                uS[lq * 4 + r][nt * 16 + lr] = (f16)fmaxf(acc[t][r] + bias, 0.f);
        }
        __syncthreads();

        acc[0] = vzero; acc[1] = vzero;
        #pragma unroll
        for (int ks = 0; ks < 4; ++ks) {
            f16x8 a = *(const f16x8*)&uS[lr][ks * 32 + lq * 8];
            const f16* wb = W2f + (size_t)blk * 16384 + (ks * 64 + l) * 8;
            #pragma unroll
            for (int t = 0; t < 2; ++t) {
                f16x8 b = *(const f16x8*)(wb + (nt0 + t) * 2048);
                acc[t] = __builtin_amdgcn_mfma_f32_16x16x32_f16(a, b, acc[t], 0, 0, 0);
            }
        }
        {
            const f16* gb = ctxoutf + (size_t)hwq * 384 + 128 + blk * 128;
            #pragma unroll
            for (int t = 0; t < 2; ++t) {
                int nt = nt0 + t;
                float bias = bb2[blk * 128 + nt * 16 + lr];
                float g = (float)gb[nt * 16 + lr];
                #pragma unroll
                for (int r = 0; r < 4; ++r) {
                    tReg[t][r] += (acc[t][r] + bias) * g;
                    tS[lq * 4 + r][nt * 16 + lr] =
                        (blk == 0) ? (f16)fmaxf(tReg[t][r], 0.f) : (f16)tReg[t][r];
                }
            }
        }
        __syncthreads();
    }

    // ---- output projection -> pS (LDS); tS holds raw t ----
    if (MODE == 0 || w < NTO) {
        f32x4 po[NPT];
        #pragma unroll
        for (int q = 0; q < NPT; ++q) po[q] = vzero;
        #pragma unroll
        for (int ks = 0; ks < 4; ++ks) {
            f16x8 a = *(const f16x8*)&tS[lr][ks * 32 + lq * 8];
            const f16* wb = Woutf + (ks * 64 + l) * 8;
            #pragma unroll
            for (int q = 0; q < NPT; ++q) {
                int nt = w + q * 4;
                f16x8 b = *(const f16x8*)(wb + nt * 2048);
                po[q] = __builtin_amdgcn_mfma_f32_16x16x32_f16(a, b, po[q], 0, 0, 0);
            }
        }
        #pragma unroll
        for (int q = 0; q < NPT; ++q) {
            int nt = w + q * 4;
            int n = nt * 16 + lr;
            if (n < NOUT) {
                float bias = boutv[n];
                #pragma unroll
                for (int r = 0; r < 4; ++r)
                    pS[lq * 4 + r][n] = (f16)(po[q][r] + bias);
            }
        }
    }
    __syncthreads();

    if (MODE == 0) {
        // ---- wave-specialized spline tail ----
        const int task = tid >> 4;   // uniform per 16-thread group; waves 0-1: tr, 2-3: id
        const int rw   = tid & 15;
        const int gm   = m0 + rw;
        float ldv, y;
        if (task < 8) {
            const int dim = task;
            const float inv_sqrt_h = 0.08838834764831845f;
            float uw[8], uh[8], udv[7];
            const f16* pr = &pS[rw][dim * 23];
            #pragma unroll
            for (int k = 0; k < 8; ++k) {
                uw[k] = (float)pr[k] * inv_sqrt_h;
                uh[k] = (float)pr[8 + k] * inv_sqrt_h;
            }
            #pragma unroll
            for (int k = 0; k < 7; ++k) udv[k] = (float)pr[16 + k];
            float ztr = zP[rw][2 * dim + 1];
            rqs1(ztr, uw, uh, udv, y, ldv);
            zg[(size_t)gm * 16 + 2 * dim + 1] = y;
        } else {
            const int dim = task - 8;
            float zid = zP[rw][2 * dim];
            rqs1_pre(zid, idk + dim * 48, y, ldv);
            zg[(size_t)gm * 16 + 2 * dim] = y;
        }
        zF[task][rw] = ldv;
        __syncthreads();
        if (tid < 16) {
            float sum = 0.f;
            #pragma unroll
            for (int t = 0; t < 16; ++t) sum += zF[t][tid];
            logq[m0 + tid] += sum;
        }
    } else {
        // ---- fused MADE scale/shift + Gaussian head ----
        const int rw = tid >> 4, d = tid & 15;
        const int gm = m0 + rw;
        const int hw = gm >> 2, b = gm & 3;
        float ar0 = (float)pS[rw][2 * d];
        float ar1 = (float)pS[rw][2 * d + 1];
        float s = softplusf(ar0) + 0.001f;
        float zn = s * zg[(size_t)gm * 16 + d] + ar1;
        float ls   = ehw[(size_t)hw * 32 + 16 + d];
        float mean = ehw[(size_t)hw * 32 + d];
        float diff = (zn - mean) * expf(-ls);
        float g = logf(s) - ls - 0.5f * diff * diff;
        g += __shfl_xor(g, 1);
        g += __shfl_xor(g, 2);
        g += __shfl_xor(g, 4);
        g += __shfl_xor(g, 8);
        if (d == 0)
            out[(size_t)b * NHW + hw] = logq[gm] + g - 14.703016531274762f;
    }
}

extern "C" void kernel_launch(void* const* d_in, const int* in_sizes, int n_in,
                              void* d_out, int out_size, void* d_ws, size_t ws_size,
                              hipStream_t stream) {
    (void)in_sizes; (void)n_in; (void)out_size; (void)ws_size;
    const float* x         = (const float*)d_in[0];
    const float* made_W0   = (const float*)d_in[1];
    const float* made_b0   = (const float*)d_in[2];
    const float* made_ctxW = (const float*)d_in[3];
    const float* made_ctxb = (const float*)d_in[4];
    const float* made_bW1  = (const float*)d_in[5];
    const float* made_bb1  = (const float*)d_in[6];
    const float* made_bW2  = (const float*)d_in[7];
    const float* made_bb2  = (const float*)d_in[8];
    const float* made_bCW  = (const float*)d_in[9];
    const float* made_bCb  = (const float*)d_in[10];
    const float* made_Wout = (const float*)d_in[11];
    const float* made_bout = (const float*)d_in[12];
    const float* sp_Win    = (const float*)d_in[13];
    const float* sp_bin    = (const float*)d_in[14];
    const float* sp_bW1    = (const float*)d_in[15];
    const float* sp_bb1    = (const float*)d_in[16];
    const float* sp_bW2    = (const float*)d_in[17];
    const float* sp_bb2    = (const float*)d_in[18];
    const float* sp_bCW    = (const float*)d_in[19];
    const float* sp_bCb    = (const float*)d_in[20];
    const float* sp_Wout   = (const float*)d_in[21];
    const float* sp_bout   = (const float*)d_in[22];
    const float* sp_uw     = (const float*)d_in[23];
    const float* sp_uh     = (const float*)d_in[24];
    const float* sp_ud     = (const float*)d_in[25];
    const float* lu_lower  = (const float*)d_in[26];
    const float* lu_upper  = (const float*)d_in[27];
    const float* lu_udiag  = (const float*)d_in[28];
    const float* lu_bias   = (const float*)d_in[29];
    const int*   lu_perm   = (const int*)d_in[30];
    const float* enc_W1    = (const float*)d_in[31];
    const float* enc_b1    = (const float*)d_in[32];
    const float* enc_W2    = (const float*)d_in[33];
    const float* enc_b2    = (const float*)d_in[34];
    float* out = (float*)d_out;

    float* ws      = (float*)d_ws;
    float* ctx     = ws;                               // 9216*128 f32
    float* z       = ctx     + (size_t)NHW * 128;      // 36864*16
    float* logq    = z       + (size_t)NROWS * 16;     // 36864
    float* thw_enc = logq    + NROWS;                  // 9216*128
    float* ehw     = thw_enc + (size_t)NHW * 128;      // 9216*32
    float* cpb     = ehw     + (size_t)NHW * 32;       // 5*384
    float* idk     = cpb     + 5 * 384;                // 4*8*48
    f16*   ctxoutf = (f16*)(idk + 1536);               // 5*9216*384 f16
    f16*   fW1f    = ctxoutf + (size_t)5 * NHW * 384;  // 8*16384
    f16*   fW2f    = fW1f    + 8 * 16384;              // 8*16384
    f16*   mW1f    = fW2f    + 8 * 16384;              // 2*16384
    f16*   mW2f    = mW1f    + 2 * 16384;              // 2*16384
    f16*   fWoutf  = mW2f    + 2 * 16384;              // 4*24576
    f16*   mWoutf  = fWoutf  + 4 * 24576;              // 4096
    f16*   finf    = mWoutf  + 4096;                   // 4*4096
    f16*   minf    = finf    + 4 * 4096;               // 4096
    f16*   cfrag   = minf    + 4096;                   // 5*49152

    dim3 B(256);
    pack_kernel<<<dim3(960, 10), B, 0, stream>>>(
        sp_bW1, sp_bW2, made_bW1, made_bW2, sp_Wout, made_Wout, sp_Win, made_W0,
        sp_bCW, made_ctxW, made_bCW, sp_bin, sp_bCb, made_ctxb, made_b0, made_bCb,
        fW1f, fW2f, mW1f, mW2f, fWoutf, mWoutf, finf, minf, cfrag, cpb);
    ctx_kernel<<<4608, B, 0, stream>>>(ctx);
    snorm_kernel<<<2304, B, 0, stream>>>(x, z);
    initlogq_kernel<<<144, B, 0, stream>>>(lu_udiag, logq);
    idknots_kernel<<<1, 64, 0, stream>>>(sp_uw, sp_uh, sp_ud, idk);

    // all ctx-dependent precomputes
    ctx_mfma<<<dim3(576, 5), B, 0, stream>>>(ctx, cfrag, cpb, ctxoutf);
    gemm_k<2><<<dim3(144, 2), B, 0, stream>>>(ctx, 128, enc_W1, 128, enc_b1, thw_enc, 128, NHW, 128, 128);
    gemm_k<0><<<dim3(144, 1), B, 0, stream>>>(thw_enc, 128, enc_W2, 128, enc_b2, ehw, 32, NHW, 32, 128);

    for (int i = 3; i >= 0; --i) {
        mega_mfma<0><<<2304, B, 0, stream>>>(z, ctxoutf + (size_t)i * NHW * 384,
                                             finf + (size_t)i * 4096,
                                             fW1f + (size_t)i * 32768, fW2f + (size_t)i * 32768,
                                             sp_bb1 + i * 256, sp_bb2 + i * 256,
                                             fWoutf + (size_t)i * 24576, sp_bout + i * 184,
                                             lu_lower + i * 256, lu_upper + i * 256,
                                             lu_udiag + i * 16, lu_bias + i * 16, lu_perm + i * 16,
                                             idk + i * 384,
                                             logq, nullptr, nullptr);
    }

    // ---- MADE + Gaussian head (fused) ----
    mega_mfma<1><<<2304, B, 0, stream>>>(z, ctxoutf + (size_t)4 * NHW * 384, minf, mW1f, mW2f,
                                         made_bb1, made_bb2, mWoutf, made_bout,
                                         nullptr, nullptr, nullptr, nullptr, nullptr, nullptr,
                                         logq, ehw, out);
}